// Round 7
// baseline (127.328 us; speedup 1.0000x reference)
//
#include <hip/hip_runtime.h>
#include <math.h>

#define V_ 3
#define B_ 2
#define C_ 32
#define D_ 32
#define H_ 128
#define W_ 160
#define HW_ (H_*W_)
#define NPIX_ (B_*H_*W_)              // 40960
#define NCOST_ (B_*D_*H_*W_)          // 1310720
#define NFEATT_ (V_*B_*H_*W_*C_)      // 3932160
#define MAXENT 256                    // max staged box entries (pixels) per view

// ---------------- 4x4 double inverse (adjugate) ----------------
__device__ __forceinline__ void inv4(const double* m, double* o) {
    double inv[16];
    inv[0]  =  m[5]*m[10]*m[15] - m[5]*m[11]*m[14] - m[9]*m[6]*m[15] + m[9]*m[7]*m[14] + m[13]*m[6]*m[11] - m[13]*m[7]*m[10];
    inv[4]  = -m[4]*m[10]*m[15] + m[4]*m[11]*m[14] + m[8]*m[6]*m[15] - m[8]*m[7]*m[14] - m[12]*m[6]*m[11] + m[12]*m[7]*m[10];
    inv[8]  =  m[4]*m[9]*m[15]  - m[4]*m[11]*m[13] - m[8]*m[5]*m[15] + m[8]*m[7]*m[13] + m[12]*m[5]*m[11] - m[12]*m[7]*m[9];
    inv[12] = -m[4]*m[9]*m[14]  + m[4]*m[10]*m[13] + m[8]*m[5]*m[14] - m[8]*m[6]*m[13] - m[12]*m[5]*m[10] + m[12]*m[6]*m[9];
    inv[1]  = -m[1]*m[10]*m[15] + m[1]*m[11]*m[14] + m[9]*m[2]*m[15] - m[9]*m[3]*m[14] - m[13]*m[2]*m[11] + m[13]*m[3]*m[10];
    inv[5]  =  m[0]*m[10]*m[15] - m[0]*m[11]*m[14] - m[8]*m[2]*m[15] + m[8]*m[3]*m[14] + m[12]*m[2]*m[11] - m[12]*m[3]*m[10];
    inv[9]  = -m[0]*m[9]*m[15]  + m[0]*m[11]*m[13] + m[8]*m[1]*m[15] - m[8]*m[3]*m[13] - m[12]*m[1]*m[11] + m[12]*m[3]*m[9];
    inv[13] =  m[0]*m[9]*m[14]  - m[0]*m[10]*m[13] - m[8]*m[1]*m[14] + m[8]*m[2]*m[13] + m[12]*m[1]*m[10] - m[12]*m[2]*m[9];
    inv[2]  =  m[1]*m[6]*m[15]  - m[1]*m[7]*m[14]  - m[5]*m[2]*m[15] + m[5]*m[3]*m[14] + m[13]*m[2]*m[7]  - m[13]*m[3]*m[6];
    inv[6]  = -m[0]*m[6]*m[15]  + m[0]*m[7]*m[14]  + m[4]*m[2]*m[15] - m[4]*m[3]*m[14] - m[12]*m[2]*m[7]  + m[12]*m[3]*m[6];
    inv[10] =  m[0]*m[5]*m[15]  - m[0]*m[7]*m[13]  - m[4]*m[1]*m[15] + m[4]*m[3]*m[13] + m[12]*m[1]*m[7]  - m[12]*m[3]*m[5];
    inv[14] = -m[0]*m[5]*m[14]  + m[0]*m[6]*m[13]  + m[4]*m[1]*m[14] - m[4]*m[2]*m[13] - m[12]*m[1]*m[6]  + m[12]*m[2]*m[5];
    inv[3]  = -m[1]*m[6]*m[11]  + m[1]*m[7]*m[10]  + m[5]*m[2]*m[11] - m[5]*m[3]*m[10] - m[9]*m[2]*m[7]   + m[9]*m[3]*m[6];
    inv[7]  =  m[0]*m[6]*m[11]  - m[0]*m[7]*m[10]  - m[4]*m[2]*m[11] + m[4]*m[3]*m[10] + m[8]*m[2]*m[7]   - m[8]*m[3]*m[6];
    inv[11] = -m[0]*m[5]*m[11]  + m[0]*m[7]*m[9]   + m[4]*m[1]*m[11] - m[4]*m[3]*m[9]  - m[8]*m[1]*m[7]   + m[8]*m[3]*m[5];
    inv[15] =  m[0]*m[5]*m[10]  - m[0]*m[6]*m[9]   - m[4]*m[1]*m[10] + m[4]*m[2]*m[9]  + m[8]*m[1]*m[6]   - m[8]*m[2]*m[5];
    double det = m[0]*inv[0] + m[1]*inv[4] + m[2]*inv[8] + m[3]*inv[12];
    det = 1.0 / det;
    for (int i = 0; i < 16; i++) o[i] = inv[i] * det;
}

__device__ __forceinline__ void mm4(const double* A, const double* Bm, double* Cm) {
    for (int r = 0; r < 4; r++)
        for (int c = 0; c < 4; c++) {
            double s = 0.0;
            for (int k = 0; k < 4; k++) s += A[r*4+k] * Bm[k*4+c];
            Cm[r*4+c] = s;
        }
}

__global__ void proj_kernel(const float* __restrict__ K, const float* __restrict__ c2w,
                            float* __restrict__ proj_out) {
    int t = blockIdx.x * blockDim.x + threadIdx.x;
    if (t >= (V_-1) * B_) return;
    int vv = t / B_;
    int b  = t % B_;
    int v  = vv + 1;
    double sc[16], rc[16];
    for (int i = 0; i < 16; i++) {
        sc[i] = (double)c2w[((size_t)v * B_ + b) * 16 + i];
        rc[i] = (double)c2w[((size_t)0 * B_ + b) * 16 + i];
    }
    double sw[16], rw[16];
    inv4(sc, sw);
    inv4(rc, rw);
    double sK[16], rK[16];
    for (int i = 0; i < 16; i++) { sK[i] = sw[i]; rK[i] = rw[i]; }
    for (int r = 0; r < 3; r++)
        for (int c = 0; c < 3; c++) {
            sK[r*4+c] = (double)K[((size_t)v * B_ + b) * 9 + r*3 + c];
            rK[r*4+c] = (double)K[((size_t)0 * B_ + b) * 9 + r*3 + c];
        }
    double sp[16], rp[16], rpi[16], P[16];
    mm4(sK, sw, sp);
    mm4(rK, rw, rp);
    inv4(rp, rpi);
    mm4(sp, rpi, P);
    float* o = proj_out + (size_t)t * 12;
    for (int r = 0; r < 3; r++)
        for (int c = 0; c < 3; c++) o[r*3+c] = (float)P[r*4+c];
    for (int r = 0; r < 3; r++) o[9+r] = (float)P[r*4+3];
}

// features (V,B,C,H,W) -> featT (V,B,H,W,C) via LDS tile (32c x 32x per block)
__global__ void __launch_bounds__(256) transpose_kernel(const float* __restrict__ feat,
                                                        float* __restrict__ featT) {
    __shared__ float lds[32][33];
    int bid = blockIdx.x;
    int xt = bid % (W_ / 32);
    int y  = (bid / (W_ / 32)) % H_;
    int vb = bid / ((W_ / 32) * H_);
    int x0 = xt * 32;
    int tid = threadIdx.x;
    int xl = tid & 31;
    int ch = tid >> 5;
#pragma unroll
    for (int it = 0; it < 4; it++) {
        int c = it * 8 + ch;
        lds[c][xl] = feat[((size_t)(vb * C_ + c) * H_ + y) * W_ + x0 + xl];
    }
    __syncthreads();
    int c4 = tid & 7;
    int xw = tid >> 3;
    float4 o;
    o.x = lds[c4*4+0][xw];
    o.y = lds[c4*4+1][xw];
    o.z = lds[c4*4+2][xw];
    o.w = lds[c4*4+3][xw];
    *(float4*)(featT + ((size_t)(vb * H_ + y) * W_ + x0 + xw) * C_ + c4 * 4) = o;
}

// bilinear weights + clamped coords from sample point (ix, iy)
struct BilW { float w00, w01, w10, w11; int xc0, xc1, yc0, yc1; };
__device__ __forceinline__ BilW bilw(float ix, float iy) {
    BilW r;
    float x0f = floorf(ix), y0f = floorf(iy);
    float wx = ix - x0f, wy = iy - y0f;
    int xi0 = (int)x0f, yi0 = (int)y0f;
    bool vx0 = (xi0 >= 0) && (xi0 <= W_ - 1);
    bool vx1 = (xi0 + 1 >= 0) && (xi0 + 1 <= W_ - 1);
    bool vy0 = (yi0 >= 0) && (yi0 <= H_ - 1);
    bool vy1 = (yi0 + 1 >= 0) && (yi0 + 1 <= H_ - 1);
    r.w00 = (vx0 && vy0) ? (1.0f - wx) * (1.0f - wy) : 0.0f;
    r.w01 = (vx1 && vy0) ? wx * (1.0f - wy) : 0.0f;
    r.w10 = (vx0 && vy1) ? (1.0f - wx) * wy : 0.0f;
    r.w11 = (vx1 && vy1) ? wx * wy : 0.0f;
    r.xc0 = min(max(xi0, 0), W_ - 1);
    r.xc1 = min(max(xi0 + 1, 0), W_ - 1);
    r.yc0 = min(max(yi0, 0), H_ - 1);
    r.yc1 = min(max(yi0 + 1, 0), H_ - 1);
    return r;
}

// cost (B,D,H,W): block = 32 consecutive pixels x 8 depths.
// Phase 1: per-(pixel,d) sample point -> LDS; block bbox per view via shfl reduce.
// Phase 2 (per view): stage the bbox feature patch into LDS cooperatively
// (coalesced VMEM), then all 4 corner gathers are conflict-free ds_read_b128.
// Fallback to global gathers for a view if its bbox exceeds MAXENT entries.
__global__ void __launch_bounds__(256, 4) cost_kernel(const float* __restrict__ featT,
                                                      const float* __restrict__ depth,
                                                      const float* __restrict__ unc,
                                                      const float* __restrict__ proj,
                                                      float* __restrict__ cost) {
    __shared__ float4 box[MAXENT * 8];     // 32 KB staged patch (one view at a time)
    __shared__ float2 sixy[2][256];        // sample points per (view, pixel, d)
    __shared__ int4   bb[2][4];            // per-wave bbox {minx,miny,maxx,maxy}
    int tid = threadIdx.x;
    const int blocksPerDt = NPIX_ / 32;    // 1280
    int dt      = blockIdx.x / blocksPerDt;
    int pixbase = (blockIdx.x % blocksPerDt) * 32;
    int d0 = dt * 8;

    const float4* fT4 = (const float4*)featT;

    // ---- phase 1 ----
    {
        int pixl = tid & 31;
        int dl   = tid >> 5;
        int pix = pixbase + pixl;
        int x = pix % W_;
        int y = (pix / W_) % H_;
        int b = pix / HW_;
        float dep = depth[((b * D_ + d0 + dl) * H_ + y) * W_ + x];
        float fx = (float)x, fy = (float)y;
        int mnx[2], mny[2], mxx[2], mxy[2];
#pragma unroll
        for (int v = 0; v < 2; v++) {
            const float* P = proj + ((size_t)v * B_ + b) * 12;
            float rx = P[0]*fx + P[1]*fy + P[2];
            float ry = P[3]*fx + P[4]*fy + P[5];
            float rz = P[6]*fx + P[7]*fy + P[8];
            float px = rx * dep + P[9];
            float py = ry * dep + P[10];
            float pz = rz * dep + P[11];
            float inv_pz = 1.0f / pz;
            float t0 = px * inv_pz;
            float t1 = py * inv_pz;
            float gx = t0 / ((W_ - 1) * 0.5f) - 1.0f;
            float gy = t1 / ((H_ - 1) * 0.5f) - 1.0f;
            float ix = ((gx + 1.0f) * W_ - 1.0f) * 0.5f;
            float iy = ((gy + 1.0f) * H_ - 1.0f) * 0.5f;
            sixy[v][tid] = make_float2(ix, iy);
            BilW w = bilw(ix, iy);
            mnx[v] = w.xc0; mxx[v] = w.xc1; mny[v] = w.yc0; mxy[v] = w.yc1;
        }
#pragma unroll
        for (int s = 1; s < 64; s <<= 1) {
#pragma unroll
            for (int v = 0; v < 2; v++) {
                mnx[v] = min(mnx[v], __shfl_xor(mnx[v], s));
                mny[v] = min(mny[v], __shfl_xor(mny[v], s));
                mxx[v] = max(mxx[v], __shfl_xor(mxx[v], s));
                mxy[v] = max(mxy[v], __shfl_xor(mxy[v], s));
            }
        }
        if ((tid & 63) == 0) {
            int w = tid >> 6;
            bb[0][w] = make_int4(mnx[0], mny[0], mxx[0], mxy[0]);
            bb[1][w] = make_int4(mnx[1], mny[1], mxx[1], mxy[1]);
        }
    }
    __syncthreads();

    // combine per-wave bboxes (all threads, block-uniform result)
    int xmn[2], ymn[2], xsp[2], area[2];
    bool fit[2];
#pragma unroll
    for (int v = 0; v < 2; v++) {
        int a = bb[v][0].x, bmn = bb[v][0].y, c = bb[v][0].z, dmx = bb[v][0].w;
#pragma unroll
        for (int w = 1; w < 4; w++) {
            a   = min(a,   bb[v][w].x);
            bmn = min(bmn, bb[v][w].y);
            c   = max(c,   bb[v][w].z);
            dmx = max(dmx, bb[v][w].w);
        }
        xmn[v] = a; ymn[v] = bmn;
        xsp[v] = c - a + 1;
        int ysp = dmx - bmn + 1;
        area[v] = xsp[v] * ysp;
        fit[v] = (area[v] <= MAXENT);
    }

    // ---- phase 2 ----
    int g  = tid >> 3;
    int c4 = tid & 7;
    int gpix = pixbase + g;
    int gx = gpix % W_;
    int gy = (gpix / W_) % H_;
    int gb = gpix / HW_;
    const float4 ref4 = fT4[(size_t)gpix * 8 + c4];
    float keepA = 0.0f, keepB = 0.0f;

#pragma unroll
    for (int v = 0; v < 2; v++) {
        int basev = ((v + 1) * B_ + gb) * HW_;
        if (fit[v]) {
            int ents = area[v] * 8;
            for (int e = tid; e < ents; e += 256) {
                int ent = e >> 3, q = e & 7;
                int yy = ymn[v] + ent / xsp[v];
                int xx = xmn[v] + ent % xsp[v];
                box[e] = fT4[(size_t)(basev + yy * W_ + xx) * 8 + q];
            }
        }
        __syncthreads();
        float kv = 0.0f;
        if (fit[v]) {
            int xm = xmn[v], ym = ymn[v], xs = xsp[v];
#pragma unroll
            for (int dl = 0; dl < 8; dl++) {
                float2 q2 = sixy[v][dl * 32 + g];
                BilW w = bilw(q2.x, q2.y);
                int r0 = (w.yc0 - ym) * xs - xm;
                int r1 = (w.yc1 - ym) * xs - xm;
                int e00 = min(max(r0 + w.xc0, 0), MAXENT - 1) * 8 + c4;
                int e01 = min(max(r0 + w.xc1, 0), MAXENT - 1) * 8 + c4;
                int e10 = min(max(r1 + w.xc0, 0), MAXENT - 1) * 8 + c4;
                int e11 = min(max(r1 + w.xc1, 0), MAXENT - 1) * 8 + c4;
                float4 a  = box[e00];
                float4 bq = box[e01];
                float4 cq = box[e10];
                float4 dq = box[e11];
                float sx = w.w00*a.x + w.w01*bq.x + w.w10*cq.x + w.w11*dq.x;
                float sy = w.w00*a.y + w.w01*bq.y + w.w10*cq.y + w.w11*dq.y;
                float sz = w.w00*a.z + w.w01*bq.z + w.w10*cq.z + w.w11*dq.z;
                float sw = w.w00*a.w + w.w01*bq.w + w.w10*cq.w + w.w11*dq.w;
                float p = ref4.x*sx + ref4.y*sy + ref4.z*sz + ref4.w*sw;
                p += __shfl_xor(p, 1);
                p += __shfl_xor(p, 2);
                p += __shfl_xor(p, 4);
                if (c4 == dl) kv = p;
            }
        } else {
#pragma unroll
            for (int dl = 0; dl < 8; dl++) {
                float2 q2 = sixy[v][dl * 32 + g];
                BilW w = bilw(q2.x, q2.y);
                float4 a  = fT4[(size_t)(basev + w.yc0 * W_ + w.xc0) * 8 + c4];
                float4 bq = fT4[(size_t)(basev + w.yc0 * W_ + w.xc1) * 8 + c4];
                float4 cq = fT4[(size_t)(basev + w.yc1 * W_ + w.xc0) * 8 + c4];
                float4 dq = fT4[(size_t)(basev + w.yc1 * W_ + w.xc1) * 8 + c4];
                float sx = w.w00*a.x + w.w01*bq.x + w.w10*cq.x + w.w11*dq.x;
                float sy = w.w00*a.y + w.w01*bq.y + w.w10*cq.y + w.w11*dq.y;
                float sz = w.w00*a.z + w.w01*bq.z + w.w10*cq.z + w.w11*dq.z;
                float sw = w.w00*a.w + w.w01*bq.w + w.w10*cq.w + w.w11*dq.w;
                float p = ref4.x*sx + ref4.y*sy + ref4.z*sz + ref4.w*sw;
                p += __shfl_xor(p, 1);
                p += __shfl_xor(p, 2);
                p += __shfl_xor(p, 4);
                if (c4 == dl) kv = p;
            }
        }
        if (v == 0) keepA = kv; else keepB = kv;
        __syncthreads();
    }

    float u = unc[gpix];
    float sig = 1.0f / (1.0f + __expf(-u));
    cost[((gb * D_ + d0 + c4) * H_ + gy) * W_ + gx] = fminf(keepA, keepB) * sig;
}

// w_feat: block = 32 pixels; 5x36 neighborhood staged in LDS (zero-padded,
// so OOB dots are naturally 0); 8 lanes per pixel; softmax over 25 dots.
__global__ void __launch_bounds__(256) wfeat_kernel(const float* __restrict__ featT,
                                                    float* __restrict__ wfeat) {
    __shared__ float4 wbox[5 * 36 * 8];   // 23 KB
    int tid = threadIdx.x;
    int g  = tid >> 3;
    int c4 = tid & 7;
    int pixbase = blockIdx.x * 32;
    int x0 = pixbase % W_;
    int yb = (pixbase / W_) % H_;
    int b  = pixbase / HW_;
    const float4* fT4 = (const float4*)featT;

    for (int e = tid; e < 5 * 36 * 8; e += 256) {
        int ent = e >> 3, q = e & 7;
        int ry = ent / 36, rx = ent - ry * 36;
        int yy = yb + ry - 2, xx = x0 + rx - 2;
        float4 val = make_float4(0.f, 0.f, 0.f, 0.f);
        if (yy >= 0 && yy < H_ && xx >= 0 && xx < W_)
            val = fT4[(size_t)((b * H_ + yy) * W_ + xx) * 8 + q];
        wbox[e] = val;
    }
    __syncthreads();

    const float4 r = wbox[(2 * 36 + g + 2) * 8 + c4];
    float logit[25];
#pragma unroll
    for (int k = 0; k < 25; k++) {
        int dy = k / 5, dx = k % 5;
        float4 q = wbox[(dy * 36 + g + dx) * 8 + c4];
        float p = r.x*q.x + r.y*q.y + r.z*q.z + r.w*q.w;
        p += __shfl_xor(p, 1);
        p += __shfl_xor(p, 2);
        p += __shfl_xor(p, 4);
        logit[k] = p;
    }
    float m = logit[0];
#pragma unroll
    for (int k = 1; k < 25; k++) m = fmaxf(m, logit[k]);
    float s = 0.0f;
#pragma unroll
    for (int k = 0; k < 25; k++) { logit[k] = __expf(logit[k] - m); s += logit[k]; }
    float inv_s = 1.0f / s;
    int pix = pixbase + g;
#pragma unroll
    for (int t = 0; t < 3; t++) {
        int k = c4 + 8 * t;
        wfeat[(size_t)k * NPIX_ + pix] = logit[k] * inv_s;
    }
    if (c4 == 0) wfeat[(size_t)24 * NPIX_ + pix] = logit[24] * inv_s;
}

// fused agg + final: block = 32 pixels (one x-run) x 32 d.
#define AG_DT(arr, dd, ry, rx) arr[((dd) * 5 + (ry)) * 36 + (rx)]
__global__ void __launch_bounds__(256) aggfinal_kernel(const float* __restrict__ depth,
                                                       const float* __restrict__ cost,
                                                       const float* __restrict__ wfeat,
                                                       float* __restrict__ out) {
    __shared__ float dtile[D_ * 5 * 36];
    __shared__ float ctile[D_ * 5 * 36];
    __shared__ float wf[25][32];
    __shared__ float aval[D_][32];
    int tid = threadIdx.x;
    int p    = tid & 31;
    int dgrp = tid >> 5;
    int pixbase = blockIdx.x * 32;
    int x0 = pixbase % W_;
    int yb = (pixbase / W_) % H_;
    int b  = pixbase / (W_ * H_);

    for (int li = tid; li < 25 * 32; li += 256) {
        int k  = li >> 5;
        int pp = li & 31;
        wf[k][pp] = wfeat[(size_t)k * NPIX_ + pixbase + pp];
    }
    for (int li = tid; li < D_ * 5 * 36; li += 256) {
        int dd  = li / 180;
        int rem = li - dd * 180;
        int ry  = rem / 36;
        int rx  = rem - ry * 36;
        int yy = yb + ry - 2;
        int xx = x0 + rx - 2;
        bool ok = (yy >= 0) && (yy < H_) && (xx >= 0) && (xx < W_);
        size_t gidx = ((size_t)(b * D_ + dd) * H_ + yy) * W_ + xx;
        dtile[li] = ok ? depth[gidx] : 0.0f;
        ctile[li] = ok ? cost[gidx]  : 0.0f;
    }
    __syncthreads();

#pragma unroll
    for (int i = 0; i < 4; i++) {
        int d = dgrp * 4 + i;
        float dc = AG_DT(dtile, d, 2, p + 2);

        float wd[25];
        float m1 = -1e30f;
#pragma unroll
        for (int k = 0; k < 25; k++) {
            int dy = k / 5, dx = k % 5;
            float nd = AG_DT(dtile, d, dy, p + dx);
            float l = -fabsf(nd - dc);
            wd[k] = l;
            m1 = fmaxf(m1, l);
        }
        float s1 = 0.0f;
#pragma unroll
        for (int k = 0; k < 25; k++) { wd[k] = __expf(wd[k] - m1); s1 += wd[k]; }
        float inv_s1 = 1.0f / s1;

        float lg[25];
        float m2 = -1e30f;
#pragma unroll
        for (int k = 0; k < 25; k++) {
            float l = (wd[k] * inv_s1) * wf[k][p];
            lg[k] = l;
            m2 = fmaxf(m2, l);
        }
        float s2 = 0.0f;
        float acc = 0.0f;
#pragma unroll
        for (int k = 0; k < 25; k++) {
            float e = __expf(lg[k] - m2);
            s2 += e;
            int dy = k / 5, dx = k % 5;
            acc += AG_DT(ctile, d, dy, p + dx) * e;
        }
        aval[d][p] = acc / s2;
    }
    __syncthreads();

    if (tid < 32) {
        float m = -1e30f;
#pragma unroll
        for (int dd = 0; dd < D_; dd++) m = fmaxf(m, aval[dd][tid]);
        float s = 0.0f, ws = 0.0f;
#pragma unroll
        for (int dd = 0; dd < D_; dd++) {
            float e = __expf(aval[dd][tid] - m);
            s += e;
            ws += e * AG_DT(dtile, dd, 2, tid + 2);
        }
        out[pixbase + tid] = ws / s;
    }
}

extern "C" void kernel_launch(void* const* d_in, const int* in_sizes, int n_in,
                              void* d_out, int out_size, void* d_ws, size_t ws_size,
                              hipStream_t stream) {
    const float* features = (const float*)d_in[0];  // (3,2,32,128,160)
    const float* intr     = (const float*)d_in[1];  // (3,2,3,3)
    const float* c2w      = (const float*)d_in[2];  // (3,2,4,4)
    const float* depth    = (const float*)d_in[3];  // (2,32,128,160)
    const float* unc      = (const float*)d_in[4];  // (2,128,160)
    float* out = (float*)d_out;

    float* ws    = (float*)d_ws;
    float* featT = ws;                          // NFEATT_
    float* cost  = featT + NFEATT_;             // NCOST_
    float* wfeat = cost + NCOST_;               // 25*NPIX_
    float* proj  = wfeat + (size_t)25 * NPIX_;  // 48

    hipLaunchKernelGGL(proj_kernel, dim3(1), dim3(64), 0, stream, intr, c2w, proj);
    hipLaunchKernelGGL(transpose_kernel, dim3(V_ * B_ * H_ * (W_ / 32)), dim3(256), 0, stream, features, featT);
    hipLaunchKernelGGL(cost_kernel, dim3((NPIX_ * 4) / 32), dim3(256), 0, stream, featT, depth, unc, proj, cost);
    hipLaunchKernelGGL(wfeat_kernel, dim3(NPIX_ / 32), dim3(256), 0, stream, featT, wfeat);
    hipLaunchKernelGGL(aggfinal_kernel, dim3(NPIX_ / 32), dim3(256), 0, stream, depth, cost, wfeat, out);
}

// Round 8
// 108.974 us; speedup vs baseline: 1.1684x; 1.1684x over previous
//
#include <hip/hip_runtime.h>
#include <math.h>

#define V_ 3
#define B_ 2
#define C_ 32
#define D_ 32
#define H_ 128
#define W_ 160
#define HW_ (H_*W_)
#define NPIX_ (B_*H_*W_)              // 40960
#define NCOST_ (B_*D_*H_*W_)          // 1310720
#define NFEATT_ (V_*B_*H_*W_*C_)      // 3932160

// ---------------- 4x4 double inverse (adjugate) ----------------
__device__ __forceinline__ void inv4(const double* m, double* o) {
    double inv[16];
    inv[0]  =  m[5]*m[10]*m[15] - m[5]*m[11]*m[14] - m[9]*m[6]*m[15] + m[9]*m[7]*m[14] + m[13]*m[6]*m[11] - m[13]*m[7]*m[10];
    inv[4]  = -m[4]*m[10]*m[15] + m[4]*m[11]*m[14] + m[8]*m[6]*m[15] - m[8]*m[7]*m[14] - m[12]*m[6]*m[11] + m[12]*m[7]*m[10];
    inv[8]  =  m[4]*m[9]*m[15]  - m[4]*m[11]*m[13] - m[8]*m[5]*m[15] + m[8]*m[7]*m[13] + m[12]*m[5]*m[11] - m[12]*m[7]*m[9];
    inv[12] = -m[4]*m[9]*m[14]  + m[4]*m[10]*m[13] + m[8]*m[5]*m[14] - m[8]*m[6]*m[13] - m[12]*m[5]*m[10] + m[12]*m[6]*m[9];
    inv[1]  = -m[1]*m[10]*m[15] + m[1]*m[11]*m[14] + m[9]*m[2]*m[15] - m[9]*m[3]*m[14] - m[13]*m[2]*m[11] + m[13]*m[3]*m[10];
    inv[5]  =  m[0]*m[10]*m[15] - m[0]*m[11]*m[14] - m[8]*m[2]*m[15] + m[8]*m[3]*m[14] + m[12]*m[2]*m[11] - m[12]*m[3]*m[10];
    inv[9]  = -m[0]*m[9]*m[15]  + m[0]*m[11]*m[13] + m[8]*m[1]*m[15] - m[8]*m[3]*m[13] - m[12]*m[1]*m[11] + m[12]*m[3]*m[9];
    inv[13] =  m[0]*m[9]*m[14]  - m[0]*m[10]*m[13] - m[8]*m[1]*m[14] + m[8]*m[2]*m[13] + m[12]*m[1]*m[10] - m[12]*m[2]*m[9];
    inv[2]  =  m[1]*m[6]*m[15]  - m[1]*m[7]*m[14]  - m[5]*m[2]*m[15] + m[5]*m[3]*m[14] + m[13]*m[2]*m[7]  - m[13]*m[3]*m[6];
    inv[6]  = -m[0]*m[6]*m[15]  + m[0]*m[7]*m[14]  + m[4]*m[2]*m[15] - m[4]*m[3]*m[14] - m[12]*m[2]*m[7]  + m[12]*m[3]*m[6];
    inv[10] =  m[0]*m[5]*m[15]  - m[0]*m[7]*m[13]  - m[4]*m[1]*m[15] + m[4]*m[3]*m[13] + m[12]*m[1]*m[7]  - m[12]*m[3]*m[5];
    inv[14] = -m[0]*m[5]*m[14]  + m[0]*m[6]*m[13]  + m[4]*m[1]*m[14] - m[4]*m[2]*m[13] - m[12]*m[1]*m[6]  + m[12]*m[2]*m[5];
    inv[3]  = -m[1]*m[6]*m[11]  + m[1]*m[7]*m[10]  + m[5]*m[2]*m[11] - m[5]*m[3]*m[10] - m[9]*m[2]*m[7]   + m[9]*m[3]*m[6];
    inv[7]  =  m[0]*m[6]*m[11]  - m[0]*m[7]*m[10]  - m[4]*m[2]*m[11] + m[4]*m[3]*m[10] + m[8]*m[2]*m[7]   - m[8]*m[3]*m[6];
    inv[11] = -m[0]*m[5]*m[11]  + m[0]*m[7]*m[9]   + m[4]*m[1]*m[11] - m[4]*m[3]*m[9]  - m[8]*m[1]*m[7]   + m[8]*m[3]*m[5];
    inv[15] =  m[0]*m[5]*m[10]  - m[0]*m[6]*m[9]   - m[4]*m[1]*m[10] + m[4]*m[2]*m[9]  + m[8]*m[1]*m[6]   - m[8]*m[2]*m[5];
    double det = m[0]*inv[0] + m[1]*inv[4] + m[2]*inv[8] + m[3]*inv[12];
    det = 1.0 / det;
    for (int i = 0; i < 16; i++) o[i] = inv[i] * det;
}

__device__ __forceinline__ void mm4(const double* A, const double* Bm, double* Cm) {
    for (int r = 0; r < 4; r++)
        for (int c = 0; c < 4; c++) {
            double s = 0.0;
            for (int k = 0; k < 4; k++) s += A[r*4+k] * Bm[k*4+c];
            Cm[r*4+c] = s;
        }
}

__global__ void proj_kernel(const float* __restrict__ K, const float* __restrict__ c2w,
                            float* __restrict__ proj_out) {
    int t = blockIdx.x * blockDim.x + threadIdx.x;
    if (t >= (V_-1) * B_) return;
    int vv = t / B_;
    int b  = t % B_;
    int v  = vv + 1;
    double sc[16], rc[16];
    for (int i = 0; i < 16; i++) {
        sc[i] = (double)c2w[((size_t)v * B_ + b) * 16 + i];
        rc[i] = (double)c2w[((size_t)0 * B_ + b) * 16 + i];
    }
    double sw[16], rw[16];
    inv4(sc, sw);
    inv4(rc, rw);
    double sK[16], rK[16];
    for (int i = 0; i < 16; i++) { sK[i] = sw[i]; rK[i] = rw[i]; }
    for (int r = 0; r < 3; r++)
        for (int c = 0; c < 3; c++) {
            sK[r*4+c] = (double)K[((size_t)v * B_ + b) * 9 + r*3 + c];
            rK[r*4+c] = (double)K[((size_t)0 * B_ + b) * 9 + r*3 + c];
        }
    double sp[16], rp[16], rpi[16], P[16];
    mm4(sK, sw, sp);
    mm4(rK, rw, rp);
    inv4(rp, rpi);
    mm4(sp, rpi, P);
    float* o = proj_out + (size_t)t * 12;
    for (int r = 0; r < 3; r++)
        for (int c = 0; c < 3; c++) o[r*3+c] = (float)P[r*4+c];
    for (int r = 0; r < 3; r++) o[9+r] = (float)P[r*4+3];
}

// features (V,B,C,H,W) -> featT (V,B,H,W,C) via LDS tile (32c x 32x per block)
__global__ void __launch_bounds__(256) transpose_kernel(const float* __restrict__ feat,
                                                        float* __restrict__ featT) {
    __shared__ float lds[32][33];
    int bid = blockIdx.x;
    int xt = bid % (W_ / 32);
    int y  = (bid / (W_ / 32)) % H_;
    int vb = bid / ((W_ / 32) * H_);
    int x0 = xt * 32;
    int tid = threadIdx.x;
    int xl = tid & 31;
    int ch = tid >> 5;
#pragma unroll
    for (int it = 0; it < 4; it++) {
        int c = it * 8 + ch;
        lds[c][xl] = feat[((size_t)(vb * C_ + c) * H_ + y) * W_ + x0 + xl];
    }
    __syncthreads();
    int c4 = tid & 7;
    int xw = tid >> 3;
    float4 o;
    o.x = lds[c4*4+0][xw];
    o.y = lds[c4*4+1][xw];
    o.z = lds[c4*4+2][xw];
    o.w = lds[c4*4+3][xw];
    *(float4*)(featT + ((size_t)(vb * H_ + y) * W_ + x0 + xw) * C_ + c4 * 4) = o;
}

// cost (B,D,H,W): block = 32 consecutive pixels x 8 depths.
// Phase 1: thread t computes projection for (pixel t&31, depth d0 + t>>5).
// Phase 2: 8-lane group owns one pixel, loops 8 depths; gathers for iteration
// dl+1 are issued BEFORE blending iteration dl (explicit double-buffering).
// XCD-aware block swizzle keeps neighboring pixel-tiles on the same XCD L2.
__global__ void __launch_bounds__(256, 4) cost_kernel(const float* __restrict__ featT,
                                                      const float* __restrict__ depth,
                                                      const float* __restrict__ unc,
                                                      const float* __restrict__ proj,
                                                      float* __restrict__ cost) {
    __shared__ float4 lw[2][256];
    __shared__ int4   lo[2][256];
    int tid = threadIdx.x;
    const int blocksPerDt = NPIX_ / 32;           // 1280; grid = 5120
    // XCD swizzle: hardware maps bid%8 -> XCD; give each XCD a contiguous chunk
    int bid  = blockIdx.x;
    int wgid = (bid & 7) * (blocksPerDt * 4 / 8) + (bid >> 3);
    int dt      = wgid / blocksPerDt;             // 0..3
    int pixbase = (wgid % blocksPerDt) * 32;
    int d0 = dt * 8;

    // ---- phase 1: projection per (pixel, d) ----
    {
        int pixl = tid & 31;
        int dl   = tid >> 5;
        int pix = pixbase + pixl;
        int x = pix % W_;
        int y = (pix / W_) % H_;
        int b = pix / HW_;
        float dep = depth[((b * D_ + d0 + dl) * H_ + y) * W_ + x];
        float fx = (float)x, fy = (float)y;
#pragma unroll
        for (int v = 0; v < 2; v++) {
            const float* P = proj + ((size_t)v * B_ + b) * 12;
            float rx = P[0]*fx + P[1]*fy + P[2];
            float ry = P[3]*fx + P[4]*fy + P[5];
            float rz = P[6]*fx + P[7]*fy + P[8];
            float px = rx * dep + P[9];
            float py = ry * dep + P[10];
            float pz = rz * dep + P[11];
            float inv_pz = 1.0f / pz;
            float t0 = px * inv_pz;
            float t1 = py * inv_pz;
            float gx = t0 / ((W_ - 1) * 0.5f) - 1.0f;
            float gy = t1 / ((H_ - 1) * 0.5f) - 1.0f;
            float ix = ((gx + 1.0f) * W_ - 1.0f) * 0.5f;
            float iy = ((gy + 1.0f) * H_ - 1.0f) * 0.5f;
            float x0f = floorf(ix), y0f = floorf(iy);
            float wx = ix - x0f, wy = iy - y0f;
            int x0 = (int)x0f, y0 = (int)y0f;
            int x1 = x0 + 1, y1 = y0 + 1;
            bool vx0 = (x0 >= 0) && (x0 <= W_ - 1);
            bool vx1 = (x1 >= 0) && (x1 <= W_ - 1);
            bool vy0 = (y0 >= 0) && (y0 <= H_ - 1);
            bool vy1 = (y1 >= 0) && (y1 <= H_ - 1);
            float4 w;
            w.x = (vx0 && vy0) ? (1.0f - wx) * (1.0f - wy) : 0.0f;
            w.y = (vx1 && vy0) ? wx * (1.0f - wy) : 0.0f;
            w.z = (vx0 && vy1) ? (1.0f - wx) * wy : 0.0f;
            w.w = (vx1 && vy1) ? wx * wy : 0.0f;
            int xc0 = min(max(x0, 0), W_ - 1), xc1 = min(max(x1, 0), W_ - 1);
            int yc0 = min(max(y0, 0), H_ - 1), yc1 = min(max(y1, 0), H_ - 1);
            int4 o;
            o.x = yc0 * W_ + xc0;
            o.y = yc0 * W_ + xc1;
            o.z = yc1 * W_ + xc0;
            o.w = yc1 * W_ + xc1;
            lw[v][tid] = w;
            lo[v][tid] = o;
        }
    }
    __syncthreads();

    // ---- phase 2: double-buffered gathers ----
    int g  = tid >> 3;
    int c4 = tid & 7;
    int pix = pixbase + g;
    int x = pix % W_;
    int y = (pix / W_) % H_;
    int b = pix / HW_;

    const float4* fT4 = (const float4*)featT;
    const float4 ref4 = fT4[(size_t)pix * 8 + c4];
    size_t base1 = (size_t)((1 * B_ + b) * HW_) * 8 + c4;
    size_t base2 = (size_t)((2 * B_ + b) * HW_) * 8 + c4;

    float u = unc[pix];
    float sig = 1.0f / (1.0f + __expf(-u));

    // preload dl=0 gathers
    int4 O0 = lo[0][g], O1 = lo[1][g];
    float4 A0 = fT4[base1 + (size_t)O0.x * 8];
    float4 B0 = fT4[base1 + (size_t)O0.y * 8];
    float4 C0 = fT4[base1 + (size_t)O0.z * 8];
    float4 E0 = fT4[base1 + (size_t)O0.w * 8];
    float4 A1 = fT4[base2 + (size_t)O1.x * 8];
    float4 B1 = fT4[base2 + (size_t)O1.y * 8];
    float4 C1 = fT4[base2 + (size_t)O1.z * 8];
    float4 E1 = fT4[base2 + (size_t)O1.w * 8];

    float myres = 0.0f;
#pragma unroll
    for (int dl = 0; dl < 8; dl++) {
        float4 W0 = lw[0][dl * 32 + g];
        float4 W1 = lw[1][dl * 32 + g];
        // issue next iteration's gathers before consuming current
        float4 nA0, nB0, nC0, nE0, nA1, nB1, nC1, nE1;
        if (dl < 7) {
            int4 P0 = lo[0][(dl + 1) * 32 + g];
            int4 P1 = lo[1][(dl + 1) * 32 + g];
            nA0 = fT4[base1 + (size_t)P0.x * 8];
            nB0 = fT4[base1 + (size_t)P0.y * 8];
            nC0 = fT4[base1 + (size_t)P0.z * 8];
            nE0 = fT4[base1 + (size_t)P0.w * 8];
            nA1 = fT4[base2 + (size_t)P1.x * 8];
            nB1 = fT4[base2 + (size_t)P1.y * 8];
            nC1 = fT4[base2 + (size_t)P1.z * 8];
            nE1 = fT4[base2 + (size_t)P1.w * 8];
        }
        float sx = W0.x*A0.x + W0.y*B0.x + W0.z*C0.x + W0.w*E0.x;
        float sy = W0.x*A0.y + W0.y*B0.y + W0.z*C0.y + W0.w*E0.y;
        float sz = W0.x*A0.z + W0.y*B0.z + W0.z*C0.z + W0.w*E0.z;
        float sw = W0.x*A0.w + W0.y*B0.w + W0.z*C0.w + W0.w*E0.w;
        float p0 = ref4.x*sx + ref4.y*sy + ref4.z*sz + ref4.w*sw;
        float tx = W1.x*A1.x + W1.y*B1.x + W1.z*C1.x + W1.w*E1.x;
        float ty = W1.x*A1.y + W1.y*B1.y + W1.z*C1.y + W1.w*E1.y;
        float tz = W1.x*A1.z + W1.y*B1.z + W1.z*C1.z + W1.w*E1.z;
        float tw = W1.x*A1.w + W1.y*B1.w + W1.z*C1.w + W1.w*E1.w;
        float p1 = ref4.x*tx + ref4.y*ty + ref4.z*tz + ref4.w*tw;
        p0 += __shfl_xor(p0, 1);
        p1 += __shfl_xor(p1, 1);
        p0 += __shfl_xor(p0, 2);
        p1 += __shfl_xor(p1, 2);
        p0 += __shfl_xor(p0, 4);
        p1 += __shfl_xor(p1, 4);
        float r = fminf(p0, p1) * sig;
        if (c4 == dl) myres = r;
        if (dl < 7) {
            A0 = nA0; B0 = nB0; C0 = nC0; E0 = nE0;
            A1 = nA1; B1 = nB1; C1 = nC1; E1 = nE1;
        }
    }
    cost[((b * D_ + d0 + c4) * H_ + y) * W_ + x] = myres;
}

// w_feat: block = 32 pixels; 5x36 neighborhood staged in LDS (zero-padded,
// so OOB dots are naturally 0); 8 lanes per pixel; softmax over 25 dots.
__global__ void __launch_bounds__(256) wfeat_kernel(const float* __restrict__ featT,
                                                    float* __restrict__ wfeat) {
    __shared__ float4 wbox[5 * 36 * 8];   // 23 KB
    int tid = threadIdx.x;
    int g  = tid >> 3;
    int c4 = tid & 7;
    int pixbase = blockIdx.x * 32;
    int x0 = pixbase % W_;
    int yb = (pixbase / W_) % H_;
    int b  = pixbase / HW_;
    const float4* fT4 = (const float4*)featT;

    for (int e = tid; e < 5 * 36 * 8; e += 256) {
        int ent = e >> 3, q = e & 7;
        int ry = ent / 36, rx = ent - ry * 36;
        int yy = yb + ry - 2, xx = x0 + rx - 2;
        float4 val = make_float4(0.f, 0.f, 0.f, 0.f);
        if (yy >= 0 && yy < H_ && xx >= 0 && xx < W_)
            val = fT4[(size_t)((b * H_ + yy) * W_ + xx) * 8 + q];
        wbox[e] = val;
    }
    __syncthreads();

    const float4 r = wbox[(2 * 36 + g + 2) * 8 + c4];
    float logit[25];
#pragma unroll
    for (int k = 0; k < 25; k++) {
        int dy = k / 5, dx = k % 5;
        float4 q = wbox[(dy * 36 + g + dx) * 8 + c4];
        float p = r.x*q.x + r.y*q.y + r.z*q.z + r.w*q.w;
        p += __shfl_xor(p, 1);
        p += __shfl_xor(p, 2);
        p += __shfl_xor(p, 4);
        logit[k] = p;
    }
    float m = logit[0];
#pragma unroll
    for (int k = 1; k < 25; k++) m = fmaxf(m, logit[k]);
    float s = 0.0f;
#pragma unroll
    for (int k = 0; k < 25; k++) { logit[k] = __expf(logit[k] - m); s += logit[k]; }
    float inv_s = 1.0f / s;
    int pix = pixbase + g;
#pragma unroll
    for (int t = 0; t < 3; t++) {
        int k = c4 + 8 * t;
        wfeat[(size_t)k * NPIX_ + pix] = logit[k] * inv_s;
    }
    if (c4 == 0) wfeat[(size_t)24 * NPIX_ + pix] = logit[24] * inv_s;
}

// fused agg + final: block = 32 pixels (one x-run) x 32 d.
#define AG_DT(arr, dd, ry, rx) arr[((dd) * 5 + (ry)) * 36 + (rx)]
__global__ void __launch_bounds__(256) aggfinal_kernel(const float* __restrict__ depth,
                                                       const float* __restrict__ cost,
                                                       const float* __restrict__ wfeat,
                                                       float* __restrict__ out) {
    __shared__ float dtile[D_ * 5 * 36];
    __shared__ float ctile[D_ * 5 * 36];
    __shared__ float wf[25][32];
    __shared__ float aval[D_][32];
    int tid = threadIdx.x;
    int p    = tid & 31;
    int dgrp = tid >> 5;
    int pixbase = blockIdx.x * 32;
    int x0 = pixbase % W_;
    int yb = (pixbase / W_) % H_;
    int b  = pixbase / (W_ * H_);

    for (int li = tid; li < 25 * 32; li += 256) {
        int k  = li >> 5;
        int pp = li & 31;
        wf[k][pp] = wfeat[(size_t)k * NPIX_ + pixbase + pp];
    }
    for (int li = tid; li < D_ * 5 * 36; li += 256) {
        int dd  = li / 180;
        int rem = li - dd * 180;
        int ry  = rem / 36;
        int rx  = rem - ry * 36;
        int yy = yb + ry - 2;
        int xx = x0 + rx - 2;
        bool ok = (yy >= 0) && (yy < H_) && (xx >= 0) && (xx < W_);
        size_t gidx = ((size_t)(b * D_ + dd) * H_ + yy) * W_ + xx;
        dtile[li] = ok ? depth[gidx] : 0.0f;
        ctile[li] = ok ? cost[gidx]  : 0.0f;
    }
    __syncthreads();

#pragma unroll
    for (int i = 0; i < 4; i++) {
        int d = dgrp * 4 + i;
        float dc = AG_DT(dtile, d, 2, p + 2);

        float wd[25];
        float m1 = -1e30f;
#pragma unroll
        for (int k = 0; k < 25; k++) {
            int dy = k / 5, dx = k % 5;
            float nd = AG_DT(dtile, d, dy, p + dx);
            float l = -fabsf(nd - dc);
            wd[k] = l;
            m1 = fmaxf(m1, l);
        }
        float s1 = 0.0f;
#pragma unroll
        for (int k = 0; k < 25; k++) { wd[k] = __expf(wd[k] - m1); s1 += wd[k]; }
        float inv_s1 = 1.0f / s1;

        float lg[25];
        float m2 = -1e30f;
#pragma unroll
        for (int k = 0; k < 25; k++) {
            float l = (wd[k] * inv_s1) * wf[k][p];
            lg[k] = l;
            m2 = fmaxf(m2, l);
        }
        float s2 = 0.0f;
        float acc = 0.0f;
#pragma unroll
        for (int k = 0; k < 25; k++) {
            float e = __expf(lg[k] - m2);
            s2 += e;
            int dy = k / 5, dx = k % 5;
            acc += AG_DT(ctile, d, dy, p + dx) * e;
        }
        aval[d][p] = acc / s2;
    }
    __syncthreads();

    if (tid < 32) {
        float m = -1e30f;
#pragma unroll
        for (int dd = 0; dd < D_; dd++) m = fmaxf(m, aval[dd][tid]);
        float s = 0.0f, ws = 0.0f;
#pragma unroll
        for (int dd = 0; dd < D_; dd++) {
            float e = __expf(aval[dd][tid] - m);
            s += e;
            ws += e * AG_DT(dtile, dd, 2, tid + 2);
        }
        out[pixbase + tid] = ws / s;
    }
}

extern "C" void kernel_launch(void* const* d_in, const int* in_sizes, int n_in,
                              void* d_out, int out_size, void* d_ws, size_t ws_size,
                              hipStream_t stream) {
    const float* features = (const float*)d_in[0];  // (3,2,32,128,160)
    const float* intr     = (const float*)d_in[1];  // (3,2,3,3)
    const float* c2w      = (const float*)d_in[2];  // (3,2,4,4)
    const float* depth    = (const float*)d_in[3];  // (2,32,128,160)
    const float* unc      = (const float*)d_in[4];  // (2,128,160)
    float* out = (float*)d_out;

    float* ws    = (float*)d_ws;
    float* featT = ws;                          // NFEATT_
    float* cost  = featT + NFEATT_;             // NCOST_
    float* wfeat = cost + NCOST_;               // 25*NPIX_
    float* proj  = wfeat + (size_t)25 * NPIX_;  // 48

    hipLaunchKernelGGL(proj_kernel, dim3(1), dim3(64), 0, stream, intr, c2w, proj);
    hipLaunchKernelGGL(transpose_kernel, dim3(V_ * B_ * H_ * (W_ / 32)), dim3(256), 0, stream, features, featT);
    hipLaunchKernelGGL(cost_kernel, dim3((NPIX_ * 4) / 32), dim3(256), 0, stream, featT, depth, unc, proj, cost);
    hipLaunchKernelGGL(wfeat_kernel, dim3(NPIX_ / 32), dim3(256), 0, stream, featT, wfeat);
    hipLaunchKernelGGL(aggfinal_kernel, dim3(NPIX_ / 32), dim3(256), 0, stream, depth, cost, wfeat, out);
}

// Round 9
// 88.658 us; speedup vs baseline: 1.4362x; 1.2292x over previous
//
#include <hip/hip_runtime.h>
#include <hip/hip_fp16.h>
#include <math.h>

#define V_ 3
#define B_ 2
#define C_ 32
#define D_ 32
#define H_ 128
#define W_ 160
#define HW_ (H_*W_)
#define NPIX_ (B_*H_*W_)              // 40960
#define NCOST_ (B_*D_*H_*W_)          // 1310720

struct H8 { __half2 h[4]; };          // 8 fp16 channels (16B)

// ---------------- 4x4 double inverse (adjugate) ----------------
__device__ __forceinline__ void inv4(const double* m, double* o) {
    double inv[16];
    inv[0]  =  m[5]*m[10]*m[15] - m[5]*m[11]*m[14] - m[9]*m[6]*m[15] + m[9]*m[7]*m[14] + m[13]*m[6]*m[11] - m[13]*m[7]*m[10];
    inv[4]  = -m[4]*m[10]*m[15] + m[4]*m[11]*m[14] + m[8]*m[6]*m[15] - m[8]*m[7]*m[14] - m[12]*m[6]*m[11] + m[12]*m[7]*m[10];
    inv[8]  =  m[4]*m[9]*m[15]  - m[4]*m[11]*m[13] - m[8]*m[5]*m[15] + m[8]*m[7]*m[13] + m[12]*m[5]*m[11] - m[12]*m[7]*m[9];
    inv[12] = -m[4]*m[9]*m[14]  + m[4]*m[10]*m[13] + m[8]*m[5]*m[14] - m[8]*m[6]*m[13] - m[12]*m[5]*m[10] + m[12]*m[6]*m[9];
    inv[1]  = -m[1]*m[10]*m[15] + m[1]*m[11]*m[14] + m[9]*m[2]*m[15] - m[9]*m[3]*m[14] - m[13]*m[2]*m[11] + m[13]*m[3]*m[10];
    inv[5]  =  m[0]*m[10]*m[15] - m[0]*m[11]*m[14] - m[8]*m[2]*m[15] + m[8]*m[3]*m[14] + m[12]*m[2]*m[11] - m[12]*m[3]*m[10];
    inv[9]  = -m[0]*m[9]*m[15]  + m[0]*m[11]*m[13] + m[8]*m[1]*m[15] - m[8]*m[3]*m[13] - m[12]*m[1]*m[11] + m[12]*m[3]*m[9];
    inv[13] =  m[0]*m[9]*m[14]  - m[0]*m[10]*m[13] - m[8]*m[1]*m[14] + m[8]*m[2]*m[13] + m[12]*m[1]*m[10] - m[12]*m[2]*m[9];
    inv[2]  =  m[1]*m[6]*m[15]  - m[1]*m[7]*m[14]  - m[5]*m[2]*m[15] + m[5]*m[3]*m[14] + m[13]*m[2]*m[7]  - m[13]*m[3]*m[6];
    inv[6]  = -m[0]*m[6]*m[15]  + m[0]*m[7]*m[14]  + m[4]*m[2]*m[15] - m[4]*m[3]*m[14] - m[12]*m[2]*m[7]  + m[12]*m[3]*m[6];
    inv[10] =  m[0]*m[5]*m[15]  - m[0]*m[7]*m[13]  - m[4]*m[1]*m[15] + m[4]*m[3]*m[13] + m[12]*m[1]*m[7]  - m[12]*m[3]*m[5];
    inv[14] = -m[0]*m[5]*m[14]  + m[0]*m[6]*m[13]  + m[4]*m[1]*m[14] - m[4]*m[2]*m[13] - m[12]*m[1]*m[6]  + m[12]*m[2]*m[5];
    inv[3]  = -m[1]*m[6]*m[11]  + m[1]*m[7]*m[10]  + m[5]*m[2]*m[11] - m[5]*m[3]*m[10] - m[9]*m[2]*m[7]   + m[9]*m[3]*m[6];
    inv[7]  =  m[0]*m[6]*m[11]  - m[0]*m[7]*m[10]  - m[4]*m[2]*m[11] + m[4]*m[3]*m[10] + m[8]*m[2]*m[7]   - m[8]*m[3]*m[6];
    inv[11] = -m[0]*m[5]*m[11]  + m[0]*m[7]*m[9]   + m[4]*m[1]*m[11] - m[4]*m[3]*m[9]  - m[8]*m[1]*m[7]   + m[8]*m[3]*m[5];
    inv[15] =  m[0]*m[5]*m[10]  - m[0]*m[6]*m[9]   - m[4]*m[1]*m[10] + m[4]*m[2]*m[9]  + m[8]*m[1]*m[6]   - m[8]*m[2]*m[5];
    double det = m[0]*inv[0] + m[1]*inv[4] + m[2]*inv[8] + m[3]*inv[12];
    det = 1.0 / det;
    for (int i = 0; i < 16; i++) o[i] = inv[i] * det;
}

__device__ __forceinline__ void mm4(const double* A, const double* Bm, double* Cm) {
    for (int r = 0; r < 4; r++)
        for (int c = 0; c < 4; c++) {
            double s = 0.0;
            for (int k = 0; k < 4; k++) s += A[r*4+k] * Bm[k*4+c];
            Cm[r*4+c] = s;
        }
}

__global__ void proj_kernel(const float* __restrict__ K, const float* __restrict__ c2w,
                            float* __restrict__ proj_out) {
    int t = blockIdx.x * blockDim.x + threadIdx.x;
    if (t >= (V_-1) * B_) return;
    int vv = t / B_;
    int b  = t % B_;
    int v  = vv + 1;
    double sc[16], rc[16];
    for (int i = 0; i < 16; i++) {
        sc[i] = (double)c2w[((size_t)v * B_ + b) * 16 + i];
        rc[i] = (double)c2w[((size_t)0 * B_ + b) * 16 + i];
    }
    double sw[16], rw[16];
    inv4(sc, sw);
    inv4(rc, rw);
    double sK[16], rK[16];
    for (int i = 0; i < 16; i++) { sK[i] = sw[i]; rK[i] = rw[i]; }
    for (int r = 0; r < 3; r++)
        for (int c = 0; c < 3; c++) {
            sK[r*4+c] = (double)K[((size_t)v * B_ + b) * 9 + r*3 + c];
            rK[r*4+c] = (double)K[((size_t)0 * B_ + b) * 9 + r*3 + c];
        }
    double sp[16], rp[16], rpi[16], P[16];
    mm4(sK, sw, sp);
    mm4(rK, rw, rp);
    inv4(rp, rpi);
    mm4(sp, rpi, P);
    float* o = proj_out + (size_t)t * 12;
    for (int r = 0; r < 3; r++)
        for (int c = 0; c < 3; c++) o[r*3+c] = (float)P[r*4+c];
    for (int r = 0; r < 3; r++) o[9+r] = (float)P[r*4+3];
}

// features (V,B,C,H,W) -> refT f32 (B,H,W,C) for view 0, fh fp16 (2,B,H,W,C)
// for views 1,2. LDS tile 32c x 32x per block.
__global__ void __launch_bounds__(256) transpose_kernel(const float* __restrict__ feat,
                                                        float* __restrict__ refT,
                                                        __half* __restrict__ fh) {
    __shared__ float lds[32][33];
    int bid = blockIdx.x;
    int xt = bid % (W_ / 32);
    int y  = (bid / (W_ / 32)) % H_;
    int vb = bid / ((W_ / 32) * H_);
    int v = vb >> 1, b = vb & 1;
    int x0 = xt * 32;
    int tid = threadIdx.x;
    int xl = tid & 31;
    int ch = tid >> 5;
#pragma unroll
    for (int it = 0; it < 4; it++) {
        int c = it * 8 + ch;
        lds[c][xl] = feat[((size_t)(vb * C_ + c) * H_ + y) * W_ + x0 + xl];
    }
    __syncthreads();
    int c4 = tid & 7;
    int xw = tid >> 3;
    float4 o;
    o.x = lds[c4*4+0][xw];
    o.y = lds[c4*4+1][xw];
    o.z = lds[c4*4+2][xw];
    o.w = lds[c4*4+3][xw];
    size_t pix = (size_t)(b * H_ + y) * W_ + x0 + xw;
    if (v == 0) {
        *(float4*)(refT + pix * C_ + c4 * 4) = o;
    } else {
        uint2 st;
        __half2 p0 = __floats2half2_rn(o.x, o.y);
        __half2 p1 = __floats2half2_rn(o.z, o.w);
        st.x = *(unsigned int*)&p0;
        st.y = *(unsigned int*)&p1;
        size_t dst = ((size_t)((v - 1) * B_ + b) * HW_ + (y * W_ + x0 + xw));
        *(uint2*)((unsigned short*)fh + dst * C_ + c4 * 4) = st;
    }
}

// cost (B,D,H,W): block = 32 consecutive pixels x 8 depths.
// Phase 1: thread t computes projection for (pixel t&31, depth d0 + t>>5).
// Phase 2: 4-lane group owns (pixel, dl-half): lane c8 covers 8 fp16 channels
// (one 16B load per corner). Blend in packed hfma2, dot vs f32 ref, 2-shfl reduce.
__global__ void __launch_bounds__(256, 4) cost_kernel(const float* __restrict__ refT,
                                                      const __half* __restrict__ fh,
                                                      const float* __restrict__ depth,
                                                      const float* __restrict__ unc,
                                                      const float* __restrict__ proj,
                                                      float* __restrict__ cost) {
    __shared__ float4 lw[2][256];
    __shared__ int4   lo[2][256];
    int tid = threadIdx.x;
    const int blocksPerDt = NPIX_ / 32;           // 1280; grid = 5120
    int dt      = blockIdx.x / blocksPerDt;       // 0..3
    int pixbase = (blockIdx.x % blocksPerDt) * 32;
    int d0 = dt * 8;

    // ---- phase 1: projection per (pixel, d) ----
    {
        int pixl = tid & 31;
        int dl   = tid >> 5;
        int pix = pixbase + pixl;
        int x = pix % W_;
        int y = (pix / W_) % H_;
        int b = pix / HW_;
        float dep = depth[((b * D_ + d0 + dl) * H_ + y) * W_ + x];
        float fx = (float)x, fy = (float)y;
#pragma unroll
        for (int v = 0; v < 2; v++) {
            const float* P = proj + ((size_t)v * B_ + b) * 12;
            float rx = P[0]*fx + P[1]*fy + P[2];
            float ry = P[3]*fx + P[4]*fy + P[5];
            float rz = P[6]*fx + P[7]*fy + P[8];
            float px = rx * dep + P[9];
            float py = ry * dep + P[10];
            float pz = rz * dep + P[11];
            float inv_pz = 1.0f / pz;
            float t0 = px * inv_pz;
            float t1 = py * inv_pz;
            float gx = t0 / ((W_ - 1) * 0.5f) - 1.0f;
            float gy = t1 / ((H_ - 1) * 0.5f) - 1.0f;
            float ix = ((gx + 1.0f) * W_ - 1.0f) * 0.5f;
            float iy = ((gy + 1.0f) * H_ - 1.0f) * 0.5f;
            float x0f = floorf(ix), y0f = floorf(iy);
            float wx = ix - x0f, wy = iy - y0f;
            int x0 = (int)x0f, y0 = (int)y0f;
            int x1 = x0 + 1, y1 = y0 + 1;
            bool vx0 = (x0 >= 0) && (x0 <= W_ - 1);
            bool vx1 = (x1 >= 0) && (x1 <= W_ - 1);
            bool vy0 = (y0 >= 0) && (y0 <= H_ - 1);
            bool vy1 = (y1 >= 0) && (y1 <= H_ - 1);
            float4 w;
            w.x = (vx0 && vy0) ? (1.0f - wx) * (1.0f - wy) : 0.0f;
            w.y = (vx1 && vy0) ? wx * (1.0f - wy) : 0.0f;
            w.z = (vx0 && vy1) ? (1.0f - wx) * wy : 0.0f;
            w.w = (vx1 && vy1) ? wx * wy : 0.0f;
            int xc0 = min(max(x0, 0), W_ - 1), xc1 = min(max(x1, 0), W_ - 1);
            int yc0 = min(max(y0, 0), H_ - 1), yc1 = min(max(y1, 0), H_ - 1);
            int4 o;
            o.x = yc0 * W_ + xc0;
            o.y = yc0 * W_ + xc1;
            o.z = yc1 * W_ + xc0;
            o.w = yc1 * W_ + xc1;
            lw[v][tid] = w;
            lo[v][tid] = o;
        }
    }
    __syncthreads();

    // ---- phase 2: fp16 gathers, 4 lanes per pixel ----
    int c8 = tid & 3;          // channel octet 0..3 (8 channels each)
    int g  = (tid >> 2) & 31;  // pixel in block
    int h  = tid >> 7;         // dl half: 0 -> d 0..3, 1 -> d 4..7
    int pix = pixbase + g;
    int x = pix % W_;
    int y = (pix / W_) % H_;
    int b = pix / HW_;

    const float4* rT4 = (const float4*)refT;
    const float4 r0 = rT4[(size_t)pix * 8 + c8 * 2];
    const float4 r1 = rT4[(size_t)pix * 8 + c8 * 2 + 1];
    const H8* fh8 = (const H8*)fh;
    size_t baseA = ((size_t)(0 * B_ + b) * HW_) * 4 + c8;   // view 1, H8 units
    size_t baseB = ((size_t)(1 * B_ + b) * HW_) * 4 + c8;   // view 2

    float u = unc[pix];
    float sig = 1.0f / (1.0f + __expf(-u));

    float myres = 0.0f;
#pragma unroll
    for (int i = 0; i < 4; i++) {
        int e = (h * 4 + i) * 32 + g;
        float pv[2];
#pragma unroll
        for (int v = 0; v < 2; v++) {
            float4 Wt = lw[v][e];
            int4   Of = lo[v][e];
            size_t base = v ? baseB : baseA;
            H8 a  = fh8[base + (size_t)Of.x * 4];
            H8 bq = fh8[base + (size_t)Of.y * 4];
            H8 cq = fh8[base + (size_t)Of.z * 4];
            H8 eq = fh8[base + (size_t)Of.w * 4];
            __half2 w0 = __float2half2_rn(Wt.x);
            __half2 w1 = __float2half2_rn(Wt.y);
            __half2 w2 = __float2half2_rn(Wt.z);
            __half2 w3 = __float2half2_rn(Wt.w);
            __half2 acc0 = __hmul2(w0, a.h[0]);
            __half2 acc1 = __hmul2(w0, a.h[1]);
            __half2 acc2 = __hmul2(w0, a.h[2]);
            __half2 acc3 = __hmul2(w0, a.h[3]);
            acc0 = __hfma2(w1, bq.h[0], acc0);
            acc1 = __hfma2(w1, bq.h[1], acc1);
            acc2 = __hfma2(w1, bq.h[2], acc2);
            acc3 = __hfma2(w1, bq.h[3], acc3);
            acc0 = __hfma2(w2, cq.h[0], acc0);
            acc1 = __hfma2(w2, cq.h[1], acc1);
            acc2 = __hfma2(w2, cq.h[2], acc2);
            acc3 = __hfma2(w2, cq.h[3], acc3);
            acc0 = __hfma2(w3, eq.h[0], acc0);
            acc1 = __hfma2(w3, eq.h[1], acc1);
            acc2 = __hfma2(w3, eq.h[2], acc2);
            acc3 = __hfma2(w3, eq.h[3], acc3);
            float2 f0 = __half22float2(acc0);
            float2 f1 = __half22float2(acc1);
            float2 f2 = __half22float2(acc2);
            float2 f3 = __half22float2(acc3);
            float p = r0.x*f0.x + r0.y*f0.y + r0.z*f1.x + r0.w*f1.y
                    + r1.x*f2.x + r1.y*f2.y + r1.z*f3.x + r1.w*f3.y;
            p += __shfl_xor(p, 1);
            p += __shfl_xor(p, 2);
            pv[v] = p;
        }
        float r = fminf(pv[0], pv[1]) * sig;
        if (c8 == i) myres = r;
    }
    cost[((b * D_ + d0 + h * 4 + c8) * H_ + y) * W_ + x] = myres;
}

// w_feat: block = 32 pixels; 5x36 f32 ref neighborhood staged in LDS
// (zero-padded -> OOB dots naturally 0); 8 lanes per pixel; softmax over 25.
__global__ void __launch_bounds__(256) wfeat_kernel(const float* __restrict__ refT,
                                                    float* __restrict__ wfeat) {
    __shared__ float4 wbox[5 * 36 * 8];   // 23 KB
    int tid = threadIdx.x;
    int g  = tid >> 3;
    int c4 = tid & 7;
    int pixbase = blockIdx.x * 32;
    int x0 = pixbase % W_;
    int yb = (pixbase / W_) % H_;
    int b  = pixbase / HW_;
    const float4* rT4 = (const float4*)refT;

    for (int e = tid; e < 5 * 36 * 8; e += 256) {
        int ent = e >> 3, q = e & 7;
        int ry = ent / 36, rx = ent - ry * 36;
        int yy = yb + ry - 2, xx = x0 + rx - 2;
        float4 val = make_float4(0.f, 0.f, 0.f, 0.f);
        if (yy >= 0 && yy < H_ && xx >= 0 && xx < W_)
            val = rT4[(size_t)((b * H_ + yy) * W_ + xx) * 8 + q];
        wbox[e] = val;
    }
    __syncthreads();

    const float4 r = wbox[(2 * 36 + g + 2) * 8 + c4];
    float logit[25];
#pragma unroll
    for (int k = 0; k < 25; k++) {
        int dy = k / 5, dx = k % 5;
        float4 q = wbox[(dy * 36 + g + dx) * 8 + c4];
        float p = r.x*q.x + r.y*q.y + r.z*q.z + r.w*q.w;
        p += __shfl_xor(p, 1);
        p += __shfl_xor(p, 2);
        p += __shfl_xor(p, 4);
        logit[k] = p;
    }
    float m = logit[0];
#pragma unroll
    for (int k = 1; k < 25; k++) m = fmaxf(m, logit[k]);
    float s = 0.0f;
#pragma unroll
    for (int k = 0; k < 25; k++) { logit[k] = __expf(logit[k] - m); s += logit[k]; }
    float inv_s = 1.0f / s;
    int pix = pixbase + g;
#pragma unroll
    for (int t = 0; t < 3; t++) {
        int k = c4 + 8 * t;
        wfeat[(size_t)k * NPIX_ + pix] = logit[k] * inv_s;
    }
    if (c4 == 0) wfeat[(size_t)24 * NPIX_ + pix] = logit[24] * inv_s;
}

// fused agg + final: block = 32 pixels (one x-run) x 32 d.
#define AG_DT(arr, dd, ry, rx) arr[((dd) * 5 + (ry)) * 36 + (rx)]
__global__ void __launch_bounds__(256) aggfinal_kernel(const float* __restrict__ depth,
                                                       const float* __restrict__ cost,
                                                       const float* __restrict__ wfeat,
                                                       float* __restrict__ out) {
    __shared__ float dtile[D_ * 5 * 36];
    __shared__ float ctile[D_ * 5 * 36];
    __shared__ float wf[25][32];
    __shared__ float aval[D_][32];
    int tid = threadIdx.x;
    int p    = tid & 31;
    int dgrp = tid >> 5;
    int pixbase = blockIdx.x * 32;
    int x0 = pixbase % W_;
    int yb = (pixbase / W_) % H_;
    int b  = pixbase / (W_ * H_);

    for (int li = tid; li < 25 * 32; li += 256) {
        int k  = li >> 5;
        int pp = li & 31;
        wf[k][pp] = wfeat[(size_t)k * NPIX_ + pixbase + pp];
    }
    for (int li = tid; li < D_ * 5 * 36; li += 256) {
        int dd  = li / 180;
        int rem = li - dd * 180;
        int ry  = rem / 36;
        int rx  = rem - ry * 36;
        int yy = yb + ry - 2;
        int xx = x0 + rx - 2;
        bool ok = (yy >= 0) && (yy < H_) && (xx >= 0) && (xx < W_);
        size_t gidx = ((size_t)(b * D_ + dd) * H_ + yy) * W_ + xx;
        dtile[li] = ok ? depth[gidx] : 0.0f;
        ctile[li] = ok ? cost[gidx]  : 0.0f;
    }
    __syncthreads();

#pragma unroll
    for (int i = 0; i < 4; i++) {
        int d = dgrp * 4 + i;
        float dc = AG_DT(dtile, d, 2, p + 2);

        float wd[25];
        float m1 = -1e30f;
#pragma unroll
        for (int k = 0; k < 25; k++) {
            int dy = k / 5, dx = k % 5;
            float nd = AG_DT(dtile, d, dy, p + dx);
            float l = -fabsf(nd - dc);
            wd[k] = l;
            m1 = fmaxf(m1, l);
        }
        float s1 = 0.0f;
#pragma unroll
        for (int k = 0; k < 25; k++) { wd[k] = __expf(wd[k] - m1); s1 += wd[k]; }
        float inv_s1 = 1.0f / s1;

        float lg[25];
        float m2 = -1e30f;
#pragma unroll
        for (int k = 0; k < 25; k++) {
            float l = (wd[k] * inv_s1) * wf[k][p];
            lg[k] = l;
            m2 = fmaxf(m2, l);
        }
        float s2 = 0.0f;
        float acc = 0.0f;
#pragma unroll
        for (int k = 0; k < 25; k++) {
            float e = __expf(lg[k] - m2);
            s2 += e;
            int dy = k / 5, dx = k % 5;
            acc += AG_DT(ctile, d, dy, p + dx) * e;
        }
        aval[d][p] = acc / s2;
    }
    __syncthreads();

    if (tid < 32) {
        float m = -1e30f;
#pragma unroll
        for (int dd = 0; dd < D_; dd++) m = fmaxf(m, aval[dd][tid]);
        float s = 0.0f, ws = 0.0f;
#pragma unroll
        for (int dd = 0; dd < D_; dd++) {
            float e = __expf(aval[dd][tid] - m);
            s += e;
            ws += e * AG_DT(dtile, dd, 2, tid + 2);
        }
        out[pixbase + tid] = ws / s;
    }
}

extern "C" void kernel_launch(void* const* d_in, const int* in_sizes, int n_in,
                              void* d_out, int out_size, void* d_ws, size_t ws_size,
                              hipStream_t stream) {
    const float* features = (const float*)d_in[0];  // (3,2,32,128,160)
    const float* intr     = (const float*)d_in[1];  // (3,2,3,3)
    const float* c2w      = (const float*)d_in[2];  // (3,2,4,4)
    const float* depth    = (const float*)d_in[3];  // (2,32,128,160)
    const float* unc      = (const float*)d_in[4];  // (2,128,160)
    float* out = (float*)d_out;

    float*  ws    = (float*)d_ws;
    float*  refT  = ws;                                         // B*HW*C f32
    __half* fh    = (__half*)(refT + (size_t)B_ * HW_ * C_);    // 2*B*HW*C fp16
    float*  cost  = (float*)(fh + (size_t)2 * B_ * HW_ * C_);   // NCOST_
    float*  wfeat = cost + NCOST_;                              // 25*NPIX_
    float*  proj  = wfeat + (size_t)25 * NPIX_;                 // 48

    hipLaunchKernelGGL(proj_kernel, dim3(1), dim3(64), 0, stream, intr, c2w, proj);
    hipLaunchKernelGGL(transpose_kernel, dim3(V_ * B_ * H_ * (W_ / 32)), dim3(256), 0, stream,
                       features, refT, fh);
    hipLaunchKernelGGL(cost_kernel, dim3((NPIX_ * 4) / 32), dim3(256), 0, stream,
                       refT, fh, depth, unc, proj, cost);
    hipLaunchKernelGGL(wfeat_kernel, dim3(NPIX_ / 32), dim3(256), 0, stream, refT, wfeat);
    hipLaunchKernelGGL(aggfinal_kernel, dim3(NPIX_ / 32), dim3(256), 0, stream, depth, cost, wfeat, out);
}

// Round 10
// 85.268 us; speedup vs baseline: 1.4933x; 1.0398x over previous
//
#include <hip/hip_runtime.h>
#include <hip/hip_fp16.h>
#include <math.h>

#define V_ 3
#define B_ 2
#define C_ 32
#define D_ 32
#define H_ 128
#define W_ 160
#define HW_ (H_*W_)
#define NPIX_ (B_*H_*W_)              // 40960
#define NCOST_ (B_*D_*H_*W_)          // 1310720

struct H8 { __half2 h[4]; };          // 8 fp16 channels (16B)

// ---------------- 4x4 double inverse (adjugate) ----------------
__device__ __forceinline__ void inv4(const double* m, double* o) {
    double inv[16];
    inv[0]  =  m[5]*m[10]*m[15] - m[5]*m[11]*m[14] - m[9]*m[6]*m[15] + m[9]*m[7]*m[14] + m[13]*m[6]*m[11] - m[13]*m[7]*m[10];
    inv[4]  = -m[4]*m[10]*m[15] + m[4]*m[11]*m[14] + m[8]*m[6]*m[15] - m[8]*m[7]*m[14] - m[12]*m[6]*m[11] + m[12]*m[7]*m[10];
    inv[8]  =  m[4]*m[9]*m[15]  - m[4]*m[11]*m[13] - m[8]*m[5]*m[15] + m[8]*m[7]*m[13] + m[12]*m[5]*m[11] - m[12]*m[7]*m[9];
    inv[12] = -m[4]*m[9]*m[14]  + m[4]*m[10]*m[13] + m[8]*m[5]*m[14] - m[8]*m[6]*m[13] - m[12]*m[5]*m[10] + m[12]*m[6]*m[9];
    inv[1]  = -m[1]*m[10]*m[15] + m[1]*m[11]*m[14] + m[9]*m[2]*m[15] - m[9]*m[3]*m[14] - m[13]*m[2]*m[11] + m[13]*m[3]*m[10];
    inv[5]  =  m[0]*m[10]*m[15] - m[0]*m[11]*m[14] - m[8]*m[2]*m[15] + m[8]*m[3]*m[14] + m[12]*m[2]*m[11] - m[12]*m[3]*m[10];
    inv[9]  = -m[0]*m[9]*m[15]  + m[0]*m[11]*m[13] + m[8]*m[1]*m[15] - m[8]*m[3]*m[13] - m[12]*m[1]*m[11] + m[12]*m[3]*m[9];
    inv[13] =  m[0]*m[9]*m[14]  - m[0]*m[10]*m[13] - m[8]*m[1]*m[14] + m[8]*m[2]*m[13] + m[12]*m[1]*m[10] - m[12]*m[2]*m[9];
    inv[2]  =  m[1]*m[6]*m[15]  - m[1]*m[7]*m[14]  - m[5]*m[2]*m[15] + m[5]*m[3]*m[14] + m[13]*m[2]*m[7]  - m[13]*m[3]*m[6];
    inv[6]  = -m[0]*m[6]*m[15]  + m[0]*m[7]*m[14]  + m[4]*m[2]*m[15] - m[4]*m[3]*m[14] - m[12]*m[2]*m[7]  + m[12]*m[3]*m[6];
    inv[10] =  m[0]*m[5]*m[15]  - m[0]*m[7]*m[13]  - m[4]*m[1]*m[15] + m[4]*m[3]*m[13] + m[12]*m[1]*m[7]  - m[12]*m[3]*m[5];
    inv[14] = -m[0]*m[5]*m[14]  + m[0]*m[6]*m[13]  + m[4]*m[1]*m[14] - m[4]*m[2]*m[13] - m[12]*m[1]*m[6]  + m[12]*m[2]*m[5];
    inv[3]  = -m[1]*m[6]*m[11]  + m[1]*m[7]*m[10]  + m[5]*m[2]*m[11] - m[5]*m[3]*m[10] - m[9]*m[2]*m[7]   + m[9]*m[3]*m[6];
    inv[7]  =  m[0]*m[6]*m[11]  - m[0]*m[7]*m[10]  - m[4]*m[2]*m[11] + m[4]*m[3]*m[10] + m[8]*m[2]*m[7]   - m[8]*m[3]*m[6];
    inv[11] = -m[0]*m[5]*m[11]  + m[0]*m[7]*m[9]   + m[4]*m[1]*m[11] - m[4]*m[3]*m[9]  - m[8]*m[1]*m[7]   + m[8]*m[3]*m[5];
    inv[15] =  m[0]*m[5]*m[10]  - m[0]*m[6]*m[9]   - m[4]*m[1]*m[10] + m[4]*m[2]*m[9]  + m[8]*m[1]*m[6]   - m[8]*m[2]*m[5];
    double det = m[0]*inv[0] + m[1]*inv[4] + m[2]*inv[8] + m[3]*inv[12];
    det = 1.0 / det;
    for (int i = 0; i < 16; i++) o[i] = inv[i] * det;
}

__device__ __forceinline__ void mm4(const double* A, const double* Bm, double* Cm) {
    for (int r = 0; r < 4; r++)
        for (int c = 0; c < 4; c++) {
            double s = 0.0;
            for (int k = 0; k < 4; k++) s += A[r*4+k] * Bm[k*4+c];
            Cm[r*4+c] = s;
        }
}

__global__ void proj_kernel(const float* __restrict__ K, const float* __restrict__ c2w,
                            float* __restrict__ proj_out) {
    int t = blockIdx.x * blockDim.x + threadIdx.x;
    if (t >= (V_-1) * B_) return;
    int vv = t / B_;
    int b  = t % B_;
    int v  = vv + 1;
    double sc[16], rc[16];
    for (int i = 0; i < 16; i++) {
        sc[i] = (double)c2w[((size_t)v * B_ + b) * 16 + i];
        rc[i] = (double)c2w[((size_t)0 * B_ + b) * 16 + i];
    }
    double sw[16], rw[16];
    inv4(sc, sw);
    inv4(rc, rw);
    double sK[16], rK[16];
    for (int i = 0; i < 16; i++) { sK[i] = sw[i]; rK[i] = rw[i]; }
    for (int r = 0; r < 3; r++)
        for (int c = 0; c < 3; c++) {
            sK[r*4+c] = (double)K[((size_t)v * B_ + b) * 9 + r*3 + c];
            rK[r*4+c] = (double)K[((size_t)0 * B_ + b) * 9 + r*3 + c];
        }
    double sp[16], rp[16], rpi[16], P[16];
    mm4(sK, sw, sp);
    mm4(rK, rw, rp);
    inv4(rp, rpi);
    mm4(sp, rpi, P);
    float* o = proj_out + (size_t)t * 12;
    for (int r = 0; r < 3; r++)
        for (int c = 0; c < 3; c++) o[r*3+c] = (float)P[r*4+c];
    for (int r = 0; r < 3; r++) o[9+r] = (float)P[r*4+3];
}

// features (V,B,C,H,W) -> refT f32 (B,H,W,C) for view 0, fh fp16 (2,B,H,W,C)
__global__ void __launch_bounds__(256) transpose_kernel(const float* __restrict__ feat,
                                                        float* __restrict__ refT,
                                                        __half* __restrict__ fh) {
    __shared__ float lds[32][33];
    int bid = blockIdx.x;
    int xt = bid % (W_ / 32);
    int y  = (bid / (W_ / 32)) % H_;
    int vb = bid / ((W_ / 32) * H_);
    int v = vb >> 1, b = vb & 1;
    int x0 = xt * 32;
    int tid = threadIdx.x;
    int xl = tid & 31;
    int ch = tid >> 5;
#pragma unroll
    for (int it = 0; it < 4; it++) {
        int c = it * 8 + ch;
        lds[c][xl] = feat[((size_t)(vb * C_ + c) * H_ + y) * W_ + x0 + xl];
    }
    __syncthreads();
    int c4 = tid & 7;
    int xw = tid >> 3;
    float4 o;
    o.x = lds[c4*4+0][xw];
    o.y = lds[c4*4+1][xw];
    o.z = lds[c4*4+2][xw];
    o.w = lds[c4*4+3][xw];
    size_t pix = (size_t)(b * H_ + y) * W_ + x0 + xw;
    if (v == 0) {
        *(float4*)(refT + pix * C_ + c4 * 4) = o;
    } else {
        uint2 st;
        __half2 p0 = __floats2half2_rn(o.x, o.y);
        __half2 p1 = __floats2half2_rn(o.z, o.w);
        st.x = *(unsigned int*)&p0;
        st.y = *(unsigned int*)&p1;
        size_t dst = ((size_t)((v - 1) * B_ + b) * HW_ + (y * W_ + x0 + xw));
        *(uint2*)((unsigned short*)fh + dst * C_ + c4 * 4) = st;
    }
}

// cost (B,D,H,W): block = 32 consecutive pixels x 8 depths (unchanged from R8).
__global__ void __launch_bounds__(256, 4) cost_kernel(const float* __restrict__ refT,
                                                      const __half* __restrict__ fh,
                                                      const float* __restrict__ depth,
                                                      const float* __restrict__ unc,
                                                      const float* __restrict__ proj,
                                                      float* __restrict__ cost) {
    __shared__ float4 lw[2][256];
    __shared__ int4   lo[2][256];
    int tid = threadIdx.x;
    const int blocksPerDt = NPIX_ / 32;           // 1280; grid = 5120
    int dt      = blockIdx.x / blocksPerDt;       // 0..3
    int pixbase = (blockIdx.x % blocksPerDt) * 32;
    int d0 = dt * 8;

    // ---- phase 1: projection per (pixel, d) ----
    {
        int pixl = tid & 31;
        int dl   = tid >> 5;
        int pix = pixbase + pixl;
        int x = pix % W_;
        int y = (pix / W_) % H_;
        int b = pix / HW_;
        float dep = depth[((b * D_ + d0 + dl) * H_ + y) * W_ + x];
        float fx = (float)x, fy = (float)y;
#pragma unroll
        for (int v = 0; v < 2; v++) {
            const float* P = proj + ((size_t)v * B_ + b) * 12;
            float rx = P[0]*fx + P[1]*fy + P[2];
            float ry = P[3]*fx + P[4]*fy + P[5];
            float rz = P[6]*fx + P[7]*fy + P[8];
            float px = rx * dep + P[9];
            float py = ry * dep + P[10];
            float pz = rz * dep + P[11];
            float inv_pz = 1.0f / pz;
            float t0 = px * inv_pz;
            float t1 = py * inv_pz;
            float gx = t0 / ((W_ - 1) * 0.5f) - 1.0f;
            float gy = t1 / ((H_ - 1) * 0.5f) - 1.0f;
            float ix = ((gx + 1.0f) * W_ - 1.0f) * 0.5f;
            float iy = ((gy + 1.0f) * H_ - 1.0f) * 0.5f;
            float x0f = floorf(ix), y0f = floorf(iy);
            float wx = ix - x0f, wy = iy - y0f;
            int x0 = (int)x0f, y0 = (int)y0f;
            int x1 = x0 + 1, y1 = y0 + 1;
            bool vx0 = (x0 >= 0) && (x0 <= W_ - 1);
            bool vx1 = (x1 >= 0) && (x1 <= W_ - 1);
            bool vy0 = (y0 >= 0) && (y0 <= H_ - 1);
            bool vy1 = (y1 >= 0) && (y1 <= H_ - 1);
            float4 w;
            w.x = (vx0 && vy0) ? (1.0f - wx) * (1.0f - wy) : 0.0f;
            w.y = (vx1 && vy0) ? wx * (1.0f - wy) : 0.0f;
            w.z = (vx0 && vy1) ? (1.0f - wx) * wy : 0.0f;
            w.w = (vx1 && vy1) ? wx * wy : 0.0f;
            int xc0 = min(max(x0, 0), W_ - 1), xc1 = min(max(x1, 0), W_ - 1);
            int yc0 = min(max(y0, 0), H_ - 1), yc1 = min(max(y1, 0), H_ - 1);
            int4 o;
            o.x = yc0 * W_ + xc0;
            o.y = yc0 * W_ + xc1;
            o.z = yc1 * W_ + xc0;
            o.w = yc1 * W_ + xc1;
            lw[v][tid] = w;
            lo[v][tid] = o;
        }
    }
    __syncthreads();

    // ---- phase 2: fp16 gathers, 4 lanes per pixel ----
    int c8 = tid & 3;
    int g  = (tid >> 2) & 31;
    int h  = tid >> 7;
    int pix = pixbase + g;
    int x = pix % W_;
    int y = (pix / W_) % H_;
    int b = pix / HW_;

    const float4* rT4 = (const float4*)refT;
    const float4 r0 = rT4[(size_t)pix * 8 + c8 * 2];
    const float4 r1 = rT4[(size_t)pix * 8 + c8 * 2 + 1];
    const H8* fh8 = (const H8*)fh;
    size_t baseA = ((size_t)(0 * B_ + b) * HW_) * 4 + c8;
    size_t baseB = ((size_t)(1 * B_ + b) * HW_) * 4 + c8;

    float u = unc[pix];
    float sig = 1.0f / (1.0f + __expf(-u));

    float myres = 0.0f;
#pragma unroll
    for (int i = 0; i < 4; i++) {
        int e = (h * 4 + i) * 32 + g;
        float pv[2];
#pragma unroll
        for (int v = 0; v < 2; v++) {
            float4 Wt = lw[v][e];
            int4   Of = lo[v][e];
            size_t base = v ? baseB : baseA;
            H8 a  = fh8[base + (size_t)Of.x * 4];
            H8 bq = fh8[base + (size_t)Of.y * 4];
            H8 cq = fh8[base + (size_t)Of.z * 4];
            H8 eq = fh8[base + (size_t)Of.w * 4];
            __half2 w0 = __float2half2_rn(Wt.x);
            __half2 w1 = __float2half2_rn(Wt.y);
            __half2 w2 = __float2half2_rn(Wt.z);
            __half2 w3 = __float2half2_rn(Wt.w);
            __half2 acc0 = __hmul2(w0, a.h[0]);
            __half2 acc1 = __hmul2(w0, a.h[1]);
            __half2 acc2 = __hmul2(w0, a.h[2]);
            __half2 acc3 = __hmul2(w0, a.h[3]);
            acc0 = __hfma2(w1, bq.h[0], acc0);
            acc1 = __hfma2(w1, bq.h[1], acc1);
            acc2 = __hfma2(w1, bq.h[2], acc2);
            acc3 = __hfma2(w1, bq.h[3], acc3);
            acc0 = __hfma2(w2, cq.h[0], acc0);
            acc1 = __hfma2(w2, cq.h[1], acc1);
            acc2 = __hfma2(w2, cq.h[2], acc2);
            acc3 = __hfma2(w2, cq.h[3], acc3);
            acc0 = __hfma2(w3, eq.h[0], acc0);
            acc1 = __hfma2(w3, eq.h[1], acc1);
            acc2 = __hfma2(w3, eq.h[2], acc2);
            acc3 = __hfma2(w3, eq.h[3], acc3);
            float2 f0 = __half22float2(acc0);
            float2 f1 = __half22float2(acc1);
            float2 f2 = __half22float2(acc2);
            float2 f3 = __half22float2(acc3);
            float p = r0.x*f0.x + r0.y*f0.y + r0.z*f1.x + r0.w*f1.y
                    + r1.x*f2.x + r1.y*f2.y + r1.z*f3.x + r1.w*f3.y;
            p += __shfl_xor(p, 1);
            p += __shfl_xor(p, 2);
            pv[v] = p;
        }
        float r = fminf(pv[0], pv[1]) * sig;
        if (c8 == i) myres = r;
    }
    cost[((b * D_ + d0 + h * 4 + c8) * H_ + y) * W_ + x] = myres;
}

// fused wfeat + agg + final: block = 32 pixels (one x-run) x 32 d.
// Phase A: stage 5x36 ref float4 box in smem, compute 25 softmax weights/pixel.
// Phase B: reuse smem for dtile+ctile (union), aggregate, softmax over D.
#define AG_DT(arr, dd, ry, rx) arr[((dd) * 5 + (ry)) * 36 + (rx)]
__global__ void __launch_bounds__(256) aggfinal_kernel(const float* __restrict__ refT,
                                                       const float* __restrict__ depth,
                                                       const float* __restrict__ cost,
                                                       float* __restrict__ out) {
    __shared__ float smem[2 * D_ * 5 * 36];   // 46 KB union: wbox (23 KB) / dtile+ctile
    __shared__ float wf[25][32];
    __shared__ float aval[D_][32];
    int tid = threadIdx.x;
    int pixbase = blockIdx.x * 32;
    int x0 = pixbase % W_;
    int yb = (pixbase / W_) % H_;
    int b  = pixbase / HW_;

    // ---- phase A: wfeat ----
    {
        float4* wbox = (float4*)smem;          // [5*36][8] float4 = 23 KB
        const float4* rT4 = (const float4*)refT;
        for (int e = tid; e < 5 * 36 * 8; e += 256) {
            int ent = e >> 3, q = e & 7;
            int ry = ent / 36, rx = ent - ry * 36;
            int yy = yb + ry - 2, xx = x0 + rx - 2;
            float4 val = make_float4(0.f, 0.f, 0.f, 0.f);
            if (yy >= 0 && yy < H_ && xx >= 0 && xx < W_)
                val = rT4[(size_t)((b * H_ + yy) * W_ + xx) * 8 + q];
            wbox[e] = val;
        }
        __syncthreads();

        int g  = tid >> 3;
        int c4 = tid & 7;
        const float4 r = wbox[(2 * 36 + g + 2) * 8 + c4];
        float logit[25];
#pragma unroll
        for (int k = 0; k < 25; k++) {
            int dy = k / 5, dx = k % 5;
            float4 q = wbox[(dy * 36 + g + dx) * 8 + c4];
            float p = r.x*q.x + r.y*q.y + r.z*q.z + r.w*q.w;
            p += __shfl_xor(p, 1);
            p += __shfl_xor(p, 2);
            p += __shfl_xor(p, 4);
            logit[k] = p;
        }
        float m = logit[0];
#pragma unroll
        for (int k = 1; k < 25; k++) m = fmaxf(m, logit[k]);
        float s = 0.0f;
#pragma unroll
        for (int k = 0; k < 25; k++) { logit[k] = __expf(logit[k] - m); s += logit[k]; }
        float inv_s = 1.0f / s;
#pragma unroll
        for (int t = 0; t < 3; t++) {
            int k = c4 + 8 * t;
            wf[k][g] = logit[k] * inv_s;
        }
        if (c4 == 0) wf[24][g] = logit[24] * inv_s;
        __syncthreads();   // all wbox reads done; smem free for reuse
    }

    // ---- phase B: agg + final ----
    float* dtile = smem;                  // D*5*36
    float* ctile = smem + D_ * 5 * 36;    // D*5*36
    for (int li = tid; li < D_ * 5 * 36; li += 256) {
        int dd  = li / 180;
        int rem = li - dd * 180;
        int ry  = rem / 36;
        int rx  = rem - ry * 36;
        int yy = yb + ry - 2;
        int xx = x0 + rx - 2;
        bool ok = (yy >= 0) && (yy < H_) && (xx >= 0) && (xx < W_);
        size_t gidx = ((size_t)(b * D_ + dd) * H_ + yy) * W_ + xx;
        dtile[li] = ok ? depth[gidx] : 0.0f;
        ctile[li] = ok ? cost[gidx]  : 0.0f;
    }
    __syncthreads();

    int p    = tid & 31;
    int dgrp = tid >> 5;
#pragma unroll
    for (int i = 0; i < 4; i++) {
        int d = dgrp * 4 + i;
        float dc = AG_DT(dtile, d, 2, p + 2);

        float wd[25];
        float m1 = -1e30f;
#pragma unroll
        for (int k = 0; k < 25; k++) {
            int dy = k / 5, dx = k % 5;
            float nd = AG_DT(dtile, d, dy, p + dx);
            float l = -fabsf(nd - dc);
            wd[k] = l;
            m1 = fmaxf(m1, l);
        }
        float s1 = 0.0f;
#pragma unroll
        for (int k = 0; k < 25; k++) { wd[k] = __expf(wd[k] - m1); s1 += wd[k]; }
        float inv_s1 = 1.0f / s1;

        float lg[25];
        float m2 = -1e30f;
#pragma unroll
        for (int k = 0; k < 25; k++) {
            float l = (wd[k] * inv_s1) * wf[k][p];
            lg[k] = l;
            m2 = fmaxf(m2, l);
        }
        float s2 = 0.0f;
        float acc = 0.0f;
#pragma unroll
        for (int k = 0; k < 25; k++) {
            float e = __expf(lg[k] - m2);
            s2 += e;
            int dy = k / 5, dx = k % 5;
            acc += AG_DT(ctile, d, dy, p + dx) * e;
        }
        aval[d][p] = acc / s2;
    }
    __syncthreads();

    if (tid < 32) {
        float m = -1e30f;
#pragma unroll
        for (int dd = 0; dd < D_; dd++) m = fmaxf(m, aval[dd][tid]);
        float s = 0.0f, ws = 0.0f;
#pragma unroll
        for (int dd = 0; dd < D_; dd++) {
            float e = __expf(aval[dd][tid] - m);
            s += e;
            ws += e * AG_DT(dtile, dd, 2, tid + 2);
        }
        out[pixbase + tid] = ws / s;
    }
}

extern "C" void kernel_launch(void* const* d_in, const int* in_sizes, int n_in,
                              void* d_out, int out_size, void* d_ws, size_t ws_size,
                              hipStream_t stream) {
    const float* features = (const float*)d_in[0];  // (3,2,32,128,160)
    const float* intr     = (const float*)d_in[1];  // (3,2,3,3)
    const float* c2w      = (const float*)d_in[2];  // (3,2,4,4)
    const float* depth    = (const float*)d_in[3];  // (2,32,128,160)
    const float* unc      = (const float*)d_in[4];  // (2,128,160)
    float* out = (float*)d_out;

    float*  ws    = (float*)d_ws;
    float*  refT  = ws;                                         // B*HW*C f32
    __half* fh    = (__half*)(refT + (size_t)B_ * HW_ * C_);    // 2*B*HW*C fp16
    float*  cost  = (float*)(fh + (size_t)2 * B_ * HW_ * C_);   // NCOST_
    float*  proj  = cost + NCOST_;                              // 48

    hipLaunchKernelGGL(proj_kernel, dim3(1), dim3(64), 0, stream, intr, c2w, proj);
    hipLaunchKernelGGL(transpose_kernel, dim3(V_ * B_ * H_ * (W_ / 32)), dim3(256), 0, stream,
                       features, refT, fh);
    hipLaunchKernelGGL(cost_kernel, dim3((NPIX_ * 4) / 32), dim3(256), 0, stream,
                       refT, fh, depth, unc, proj, cost);
    hipLaunchKernelGGL(aggfinal_kernel, dim3(NPIX_ / 32), dim3(256), 0, stream,
                       refT, depth, cost, out);
}

// Round 11
// 82.219 us; speedup vs baseline: 1.5486x; 1.0371x over previous
//
#include <hip/hip_runtime.h>
#include <hip/hip_fp16.h>
#include <math.h>

#define V_ 3
#define B_ 2
#define C_ 32
#define D_ 32
#define H_ 128
#define W_ 160
#define HW_ (H_*W_)
#define NPIX_ (B_*H_*W_)              // 40960
#define NCOST_ (B_*D_*H_*W_)          // 1310720

struct H8 { __half2 h[4]; };          // 8 fp16 channels (16B)

// ---------------- 4x4 double inverse (adjugate) ----------------
__device__ __forceinline__ void inv4(const double* m, double* o) {
    double inv[16];
    inv[0]  =  m[5]*m[10]*m[15] - m[5]*m[11]*m[14] - m[9]*m[6]*m[15] + m[9]*m[7]*m[14] + m[13]*m[6]*m[11] - m[13]*m[7]*m[10];
    inv[4]  = -m[4]*m[10]*m[15] + m[4]*m[11]*m[14] + m[8]*m[6]*m[15] - m[8]*m[7]*m[14] - m[12]*m[6]*m[11] + m[12]*m[7]*m[10];
    inv[8]  =  m[4]*m[9]*m[15]  - m[4]*m[11]*m[13] - m[8]*m[5]*m[15] + m[8]*m[7]*m[13] + m[12]*m[5]*m[11] - m[12]*m[7]*m[9];
    inv[12] = -m[4]*m[9]*m[14]  + m[4]*m[10]*m[13] + m[8]*m[5]*m[14] - m[8]*m[6]*m[13] - m[12]*m[5]*m[10] + m[12]*m[6]*m[9];
    inv[1]  = -m[1]*m[10]*m[15] + m[1]*m[11]*m[14] + m[9]*m[2]*m[15] - m[9]*m[3]*m[14] - m[13]*m[2]*m[11] + m[13]*m[3]*m[10];
    inv[5]  =  m[0]*m[10]*m[15] - m[0]*m[11]*m[14] - m[8]*m[2]*m[15] + m[8]*m[3]*m[14] + m[12]*m[2]*m[11] - m[12]*m[3]*m[10];
    inv[9]  = -m[0]*m[9]*m[15]  + m[0]*m[11]*m[13] + m[8]*m[1]*m[15] - m[8]*m[3]*m[13] - m[12]*m[1]*m[11] + m[12]*m[3]*m[9];
    inv[13] =  m[0]*m[9]*m[14]  - m[0]*m[10]*m[13] - m[8]*m[1]*m[14] + m[8]*m[2]*m[13] + m[12]*m[1]*m[10] - m[12]*m[2]*m[9];
    inv[2]  =  m[1]*m[6]*m[15]  - m[1]*m[7]*m[14]  - m[5]*m[2]*m[15] + m[5]*m[3]*m[14] + m[13]*m[2]*m[7]  - m[13]*m[3]*m[6];
    inv[6]  = -m[0]*m[6]*m[15]  + m[0]*m[7]*m[14]  + m[4]*m[2]*m[15] - m[4]*m[3]*m[14] - m[12]*m[2]*m[7]  + m[12]*m[3]*m[6];
    inv[10] =  m[0]*m[5]*m[15]  - m[0]*m[7]*m[13]  - m[4]*m[1]*m[15] + m[4]*m[3]*m[13] + m[12]*m[1]*m[7]  - m[12]*m[3]*m[5];
    inv[14] = -m[0]*m[5]*m[14]  + m[0]*m[6]*m[13]  + m[4]*m[1]*m[14] - m[4]*m[2]*m[13] - m[12]*m[1]*m[6]  + m[12]*m[2]*m[5];
    inv[3]  = -m[1]*m[6]*m[11]  + m[1]*m[7]*m[10]  + m[5]*m[2]*m[11] - m[5]*m[3]*m[10] - m[9]*m[2]*m[7]   + m[9]*m[3]*m[6];
    inv[7]  =  m[0]*m[6]*m[11]  - m[0]*m[7]*m[10]  - m[4]*m[2]*m[11] + m[4]*m[3]*m[10] + m[8]*m[2]*m[7]   - m[8]*m[3]*m[6];
    inv[11] = -m[0]*m[5]*m[11]  + m[0]*m[7]*m[9]   + m[4]*m[1]*m[11] - m[4]*m[3]*m[9]  - m[8]*m[1]*m[7]   + m[8]*m[3]*m[5];
    inv[15] =  m[0]*m[5]*m[10]  - m[0]*m[6]*m[9]   - m[4]*m[1]*m[10] + m[4]*m[2]*m[9]  + m[8]*m[1]*m[6]   - m[8]*m[2]*m[5];
    double det = m[0]*inv[0] + m[1]*inv[4] + m[2]*inv[8] + m[3]*inv[12];
    det = 1.0 / det;
    for (int i = 0; i < 16; i++) o[i] = inv[i] * det;
}

__device__ __forceinline__ void mm4(const double* A, const double* Bm, double* Cm) {
    for (int r = 0; r < 4; r++)
        for (int c = 0; c < 4; c++) {
            double s = 0.0;
            for (int k = 0; k < 4; k++) s += A[r*4+k] * Bm[k*4+c];
            Cm[r*4+c] = s;
        }
}

__global__ void proj_kernel(const float* __restrict__ K, const float* __restrict__ c2w,
                            float* __restrict__ proj_out) {
    int t = blockIdx.x * blockDim.x + threadIdx.x;
    if (t >= (V_-1) * B_) return;
    int vv = t / B_;
    int b  = t % B_;
    int v  = vv + 1;
    double sc[16], rc[16];
    for (int i = 0; i < 16; i++) {
        sc[i] = (double)c2w[((size_t)v * B_ + b) * 16 + i];
        rc[i] = (double)c2w[((size_t)0 * B_ + b) * 16 + i];
    }
    double sw[16], rw[16];
    inv4(sc, sw);
    inv4(rc, rw);
    double sK[16], rK[16];
    for (int i = 0; i < 16; i++) { sK[i] = sw[i]; rK[i] = rw[i]; }
    for (int r = 0; r < 3; r++)
        for (int c = 0; c < 3; c++) {
            sK[r*4+c] = (double)K[((size_t)v * B_ + b) * 9 + r*3 + c];
            rK[r*4+c] = (double)K[((size_t)0 * B_ + b) * 9 + r*3 + c];
        }
    double sp[16], rp[16], rpi[16], P[16];
    mm4(sK, sw, sp);
    mm4(rK, rw, rp);
    inv4(rp, rpi);
    mm4(sp, rpi, P);
    float* o = proj_out + (size_t)t * 12;
    for (int r = 0; r < 3; r++)
        for (int c = 0; c < 3; c++) o[r*3+c] = (float)P[r*4+c];
    for (int r = 0; r < 3; r++) o[9+r] = (float)P[r*4+3];
}

// features (V,B,C,H,W) -> refT f32 (B,H,W,C) for view 0, fh fp16 (2,B,H,W,C)
__global__ void __launch_bounds__(256) transpose_kernel(const float* __restrict__ feat,
                                                        float* __restrict__ refT,
                                                        __half* __restrict__ fh) {
    __shared__ float lds[32][33];
    int bid = blockIdx.x;
    int xt = bid % (W_ / 32);
    int y  = (bid / (W_ / 32)) % H_;
    int vb = bid / ((W_ / 32) * H_);
    int v = vb >> 1, b = vb & 1;
    int x0 = xt * 32;
    int tid = threadIdx.x;
    int xl = tid & 31;
    int ch = tid >> 5;
#pragma unroll
    for (int it = 0; it < 4; it++) {
        int c = it * 8 + ch;
        lds[c][xl] = feat[((size_t)(vb * C_ + c) * H_ + y) * W_ + x0 + xl];
    }
    __syncthreads();
    int c4 = tid & 7;
    int xw = tid >> 3;
    float4 o;
    o.x = lds[c4*4+0][xw];
    o.y = lds[c4*4+1][xw];
    o.z = lds[c4*4+2][xw];
    o.w = lds[c4*4+3][xw];
    size_t pix = (size_t)(b * H_ + y) * W_ + x0 + xw;
    if (v == 0) {
        *(float4*)(refT + pix * C_ + c4 * 4) = o;
    } else {
        uint2 st;
        __half2 p0 = __floats2half2_rn(o.x, o.y);
        __half2 p1 = __floats2half2_rn(o.z, o.w);
        st.x = *(unsigned int*)&p0;
        st.y = *(unsigned int*)&p1;
        size_t dst = ((size_t)((v - 1) * B_ + b) * HW_ + (y * W_ + x0 + xw));
        *(uint2*)((unsigned short*)fh + dst * C_ + c4 * 4) = st;
    }
}

// cost (B,D,H,W): block = 32 consecutive pixels x 8 depths (unchanged from R8).
__global__ void __launch_bounds__(256, 4) cost_kernel(const float* __restrict__ refT,
                                                      const __half* __restrict__ fh,
                                                      const float* __restrict__ depth,
                                                      const float* __restrict__ unc,
                                                      const float* __restrict__ proj,
                                                      float* __restrict__ cost) {
    __shared__ float4 lw[2][256];
    __shared__ int4   lo[2][256];
    int tid = threadIdx.x;
    const int blocksPerDt = NPIX_ / 32;           // 1280; grid = 5120
    int dt      = blockIdx.x / blocksPerDt;       // 0..3
    int pixbase = (blockIdx.x % blocksPerDt) * 32;
    int d0 = dt * 8;

    // ---- phase 1: projection per (pixel, d) ----
    {
        int pixl = tid & 31;
        int dl   = tid >> 5;
        int pix = pixbase + pixl;
        int x = pix % W_;
        int y = (pix / W_) % H_;
        int b = pix / HW_;
        float dep = depth[((b * D_ + d0 + dl) * H_ + y) * W_ + x];
        float fx = (float)x, fy = (float)y;
#pragma unroll
        for (int v = 0; v < 2; v++) {
            const float* P = proj + ((size_t)v * B_ + b) * 12;
            float rx = P[0]*fx + P[1]*fy + P[2];
            float ry = P[3]*fx + P[4]*fy + P[5];
            float rz = P[6]*fx + P[7]*fy + P[8];
            float px = rx * dep + P[9];
            float py = ry * dep + P[10];
            float pz = rz * dep + P[11];
            float inv_pz = 1.0f / pz;
            float t0 = px * inv_pz;
            float t1 = py * inv_pz;
            float gx = t0 / ((W_ - 1) * 0.5f) - 1.0f;
            float gy = t1 / ((H_ - 1) * 0.5f) - 1.0f;
            float ix = ((gx + 1.0f) * W_ - 1.0f) * 0.5f;
            float iy = ((gy + 1.0f) * H_ - 1.0f) * 0.5f;
            float x0f = floorf(ix), y0f = floorf(iy);
            float wx = ix - x0f, wy = iy - y0f;
            int x0 = (int)x0f, y0 = (int)y0f;
            int x1 = x0 + 1, y1 = y0 + 1;
            bool vx0 = (x0 >= 0) && (x0 <= W_ - 1);
            bool vx1 = (x1 >= 0) && (x1 <= W_ - 1);
            bool vy0 = (y0 >= 0) && (y0 <= H_ - 1);
            bool vy1 = (y1 >= 0) && (y1 <= H_ - 1);
            float4 w;
            w.x = (vx0 && vy0) ? (1.0f - wx) * (1.0f - wy) : 0.0f;
            w.y = (vx1 && vy0) ? wx * (1.0f - wy) : 0.0f;
            w.z = (vx0 && vy1) ? (1.0f - wx) * wy : 0.0f;
            w.w = (vx1 && vy1) ? wx * wy : 0.0f;
            int xc0 = min(max(x0, 0), W_ - 1), xc1 = min(max(x1, 0), W_ - 1);
            int yc0 = min(max(y0, 0), H_ - 1), yc1 = min(max(y1, 0), H_ - 1);
            int4 o;
            o.x = yc0 * W_ + xc0;
            o.y = yc0 * W_ + xc1;
            o.z = yc1 * W_ + xc0;
            o.w = yc1 * W_ + xc1;
            lw[v][tid] = w;
            lo[v][tid] = o;
        }
    }
    __syncthreads();

    // ---- phase 2: fp16 gathers, 4 lanes per pixel ----
    int c8 = tid & 3;
    int g  = (tid >> 2) & 31;
    int h  = tid >> 7;
    int pix = pixbase + g;
    int x = pix % W_;
    int y = (pix / W_) % H_;
    int b = pix / HW_;

    const float4* rT4 = (const float4*)refT;
    const float4 r0 = rT4[(size_t)pix * 8 + c8 * 2];
    const float4 r1 = rT4[(size_t)pix * 8 + c8 * 2 + 1];
    const H8* fh8 = (const H8*)fh;
    size_t baseA = ((size_t)(0 * B_ + b) * HW_) * 4 + c8;
    size_t baseB = ((size_t)(1 * B_ + b) * HW_) * 4 + c8;

    float u = unc[pix];
    float sig = 1.0f / (1.0f + __expf(-u));

    float myres = 0.0f;
#pragma unroll
    for (int i = 0; i < 4; i++) {
        int e = (h * 4 + i) * 32 + g;
        float pv[2];
#pragma unroll
        for (int v = 0; v < 2; v++) {
            float4 Wt = lw[v][e];
            int4   Of = lo[v][e];
            size_t base = v ? baseB : baseA;
            H8 a  = fh8[base + (size_t)Of.x * 4];
            H8 bq = fh8[base + (size_t)Of.y * 4];
            H8 cq = fh8[base + (size_t)Of.z * 4];
            H8 eq = fh8[base + (size_t)Of.w * 4];
            __half2 w0 = __float2half2_rn(Wt.x);
            __half2 w1 = __float2half2_rn(Wt.y);
            __half2 w2 = __float2half2_rn(Wt.z);
            __half2 w3 = __float2half2_rn(Wt.w);
            __half2 acc0 = __hmul2(w0, a.h[0]);
            __half2 acc1 = __hmul2(w0, a.h[1]);
            __half2 acc2 = __hmul2(w0, a.h[2]);
            __half2 acc3 = __hmul2(w0, a.h[3]);
            acc0 = __hfma2(w1, bq.h[0], acc0);
            acc1 = __hfma2(w1, bq.h[1], acc1);
            acc2 = __hfma2(w1, bq.h[2], acc2);
            acc3 = __hfma2(w1, bq.h[3], acc3);
            acc0 = __hfma2(w2, cq.h[0], acc0);
            acc1 = __hfma2(w2, cq.h[1], acc1);
            acc2 = __hfma2(w2, cq.h[2], acc2);
            acc3 = __hfma2(w2, cq.h[3], acc3);
            acc0 = __hfma2(w3, eq.h[0], acc0);
            acc1 = __hfma2(w3, eq.h[1], acc1);
            acc2 = __hfma2(w3, eq.h[2], acc2);
            acc3 = __hfma2(w3, eq.h[3], acc3);
            float2 f0 = __half22float2(acc0);
            float2 f1 = __half22float2(acc1);
            float2 f2 = __half22float2(acc2);
            float2 f3 = __half22float2(acc3);
            float p = r0.x*f0.x + r0.y*f0.y + r0.z*f1.x + r0.w*f1.y
                    + r1.x*f2.x + r1.y*f2.y + r1.z*f3.x + r1.w*f3.y;
            p += __shfl_xor(p, 1);
            p += __shfl_xor(p, 2);
            pv[v] = p;
        }
        float r = fminf(pv[0], pv[1]) * sig;
        if (c8 == i) myres = r;
    }
    cost[((b * D_ + d0 + h * 4 + c8) * H_ + y) * W_ + x] = myres;
}

// fused wfeat + agg + final: block = 8x x 4y pixel tile (32 px) x 32 d.
// Phase A: stage 8x12 ref float4 box (entry stride 9 to spread banks),
//          compute 25 softmax weights per pixel.
// Phase B: reuse smem for dtile+ctile [32][8][16], aggregate, softmax over D.
#define TX_ 8
#define TY_ 4
#define AG(arr, dd, ry, rx) arr[((((dd) * 8 + (ry)) << 4) + (rx))]
__global__ void __launch_bounds__(256) aggfinal_kernel(const float* __restrict__ refT,
                                                       const float* __restrict__ depth,
                                                       const float* __restrict__ cost,
                                                       float* __restrict__ out) {
    __shared__ float smem[2 * D_ * 8 * 16];   // 32 KB union: wbox / dtile+ctile
    __shared__ float wf[25][32];
    __shared__ float aval[D_][32];
    int tid = threadIdx.x;
    int bid = blockIdx.x;
    const int XT = W_ / TX_;                  // 20
    int xt = bid % XT;
    int yt = (bid / XT) % (H_ / TY_);
    int b  = bid / (XT * (H_ / TY_));
    int x0 = xt * TX_;
    int yb = yt * TY_;

    // ---- phase A: wfeat (8 rows x 12 cols ref box) ----
    {
        float4* wbox = (float4*)smem;         // entries stride 9 float4
        const float4* rT4 = (const float4*)refT;
        for (int e = tid; e < 8 * 12 * 8; e += 256) {
            int ent = e >> 3, q = e & 7;
            int ry = ent / 12, rx = ent - ry * 12;
            int yy = yb + ry - 2, xx = x0 + rx - 2;
            float4 val = make_float4(0.f, 0.f, 0.f, 0.f);
            if (yy >= 0 && yy < H_ && xx >= 0 && xx < W_)
                val = rT4[(size_t)((b * H_ + yy) * W_ + xx) * 8 + q];
            wbox[ent * 9 + q] = val;
        }
        __syncthreads();

        int g  = tid >> 3;        // 0..31: px = g&7, py = g>>3
        int c4 = tid & 7;
        int px = g & 7, py = g >> 3;
        const float4 r = wbox[((py + 2) * 12 + px + 2) * 9 + c4];
        float logit[25];
#pragma unroll
        for (int k = 0; k < 25; k++) {
            int dy = k / 5, dx = k % 5;
            float4 q = wbox[((py + dy) * 12 + px + dx) * 9 + c4];
            float p = r.x*q.x + r.y*q.y + r.z*q.z + r.w*q.w;
            p += __shfl_xor(p, 1);
            p += __shfl_xor(p, 2);
            p += __shfl_xor(p, 4);
            logit[k] = p;
        }
        float m = logit[0];
#pragma unroll
        for (int k = 1; k < 25; k++) m = fmaxf(m, logit[k]);
        float s = 0.0f;
#pragma unroll
        for (int k = 0; k < 25; k++) { logit[k] = __expf(logit[k] - m); s += logit[k]; }
        float inv_s = 1.0f / s;
#pragma unroll
        for (int t = 0; t < 3; t++) {
            int k = c4 + 8 * t;
            wf[k][g] = logit[k] * inv_s;
        }
        if (c4 == 0) wf[24][g] = logit[24] * inv_s;
        __syncthreads();   // all wbox reads done; smem free for reuse
    }

    // ---- phase B: agg + final ----
    float* dtile = smem;                       // [32][8][16]
    float* ctile = smem + D_ * 8 * 16;         // [32][8][16]
    for (int li = tid; li < D_ * 8 * 12; li += 256) {
        int dd  = li / 96;
        int rem = li - dd * 96;
        int ry  = rem / 12;
        int rx  = rem - ry * 12;
        int yy = yb + ry - 2;
        int xx = x0 + rx - 2;
        bool ok = (yy >= 0) && (yy < H_) && (xx >= 0) && (xx < W_);
        size_t gidx = ((size_t)(b * D_ + dd) * H_ + yy) * W_ + xx;
        AG(dtile, dd, ry, rx) = ok ? depth[gidx] : 0.0f;
        AG(ctile, dd, ry, rx) = ok ? cost[gidx]  : 0.0f;
    }
    __syncthreads();

    int p    = tid & 31;
    int px = p & 7, py = p >> 3;
    int dgrp = tid >> 5;
#pragma unroll
    for (int i = 0; i < 4; i++) {
        int d = dgrp * 4 + i;
        float dc = AG(dtile, d, py + 2, px + 2);

        float wd[25];
        float m1 = -1e30f;
#pragma unroll
        for (int k = 0; k < 25; k++) {
            int dy = k / 5, dx = k % 5;
            float nd = AG(dtile, d, py + dy, px + dx);
            float l = -fabsf(nd - dc);
            wd[k] = l;
            m1 = fmaxf(m1, l);
        }
        float s1 = 0.0f;
#pragma unroll
        for (int k = 0; k < 25; k++) { wd[k] = __expf(wd[k] - m1); s1 += wd[k]; }
        float inv_s1 = 1.0f / s1;

        float lg[25];
        float m2 = -1e30f;
#pragma unroll
        for (int k = 0; k < 25; k++) {
            float l = (wd[k] * inv_s1) * wf[k][p];
            lg[k] = l;
            m2 = fmaxf(m2, l);
        }
        float s2 = 0.0f;
        float acc = 0.0f;
#pragma unroll
        for (int k = 0; k < 25; k++) {
            float e = __expf(lg[k] - m2);
            s2 += e;
            int dy = k / 5, dx = k % 5;
            acc += AG(ctile, d, dy + py, dx + px) * e;
        }
        aval[d][p] = acc / s2;
    }
    __syncthreads();

    if (tid < 32) {
        int qx = tid & 7, qy = tid >> 3;
        float m = -1e30f;
#pragma unroll
        for (int dd = 0; dd < D_; dd++) m = fmaxf(m, aval[dd][tid]);
        float s = 0.0f, ws = 0.0f;
#pragma unroll
        for (int dd = 0; dd < D_; dd++) {
            float e = __expf(aval[dd][tid] - m);
            s += e;
            ws += e * AG(dtile, dd, qy + 2, qx + 2);
        }
        out[(b * H_ + yb + qy) * W_ + x0 + qx] = ws / s;
    }
}

extern "C" void kernel_launch(void* const* d_in, const int* in_sizes, int n_in,
                              void* d_out, int out_size, void* d_ws, size_t ws_size,
                              hipStream_t stream) {
    const float* features = (const float*)d_in[0];  // (3,2,32,128,160)
    const float* intr     = (const float*)d_in[1];  // (3,2,3,3)
    const float* c2w      = (const float*)d_in[2];  // (3,2,4,4)
    const float* depth    = (const float*)d_in[3];  // (2,32,128,160)
    const float* unc      = (const float*)d_in[4];  // (2,128,160)
    float* out = (float*)d_out;

    float*  ws    = (float*)d_ws;
    float*  refT  = ws;                                         // B*HW*C f32
    __half* fh    = (__half*)(refT + (size_t)B_ * HW_ * C_);    // 2*B*HW*C fp16
    float*  cost  = (float*)(fh + (size_t)2 * B_ * HW_ * C_);   // NCOST_
    float*  proj  = cost + NCOST_;                              // 48

    hipLaunchKernelGGL(proj_kernel, dim3(1), dim3(64), 0, stream, intr, c2w, proj);
    hipLaunchKernelGGL(transpose_kernel, dim3(V_ * B_ * H_ * (W_ / 32)), dim3(256), 0, stream,
                       features, refT, fh);
    hipLaunchKernelGGL(cost_kernel, dim3((NPIX_ * 4) / 32), dim3(256), 0, stream,
                       refT, fh, depth, unc, proj, cost);
    hipLaunchKernelGGL(aggfinal_kernel, dim3(NPIX_ / (TX_ * TY_)), dim3(256), 0, stream,
                       refT, depth, cost, out);
}